// Round 11
// baseline (316.816 us; speedup 1.0000x reference)
//
#include <hip/hip_runtime.h>
#include <cmath>

namespace {

using f16 = _Float16;
typedef f16 f16x8 __attribute__((ext_vector_type(8)));
typedef f16 f16x4 __attribute__((ext_vector_type(4)));
typedef __fp16 h16x2 __attribute__((ext_vector_type(2)));
typedef float f32x4 __attribute__((ext_vector_type(4)));

constexpr int FE = 1216, FN = 1108, MD = 256, KC = 600;
constexpr int PAIRS = 65536, ROWS = 1024;

// workspace offsets (float units, all 16B-aligned)
constexpr size_t OFF_XP    = 0;                       // fp32 [1024][256]
constexpr size_t OFF_XPF   = OFF_XP    + 262144;      // f16  [1024][256]
constexpr size_t OFF_XPH   = OFF_XPF   + 131072;      // fp32 [1024][256]
constexpr size_t OFF_S1    = OFF_XPH   + 262144;      // fp32 [65536]
constexpr size_t OFF_S2    = OFF_S1    + 65536;       // (unused)
constexpr size_t OFF_XF    = OFF_S2    + 65536;       // f16  [1024][256]
constexpr size_t OFF_GI    = OFF_XF    + 131072;      // fp32 [1024][768]
constexpr size_t OFF_GH    = OFF_GI    + 786432;      // fp32 [1024][768]
constexpr size_t OFF_HNF   = OFF_GH    + 786432;      // (unused)
constexpr size_t OFF_WER8  = OFF_HNF   + 131072;      // f16 prefrag 152*256*8
constexpr size_t OFF_WNR8  = OFF_WER8  + 155648;      // 144*256*8
constexpr size_t OFF_WEV8  = OFF_WNR8  + 147456;      // 32*256*8
constexpr size_t OFF_WHW8  = OFF_WEV8  + 32768;       // 32*256*8
constexpr size_t OFF_WL18  = OFF_WHW8  + 32768;       // 32*256*8
constexpr size_t OFF_WI8   = OFF_WL18  + 32768;       // 32*768*8
constexpr size_t OFF_WH8   = OFF_WI8   + 98304;       // 32*768*8
constexpr size_t OFF_WRO8  = OFF_WH8   + 98304;       // 32*768*8 (KC pad 768)
constexpr size_t OFF_E0H   = OFF_WRO8  + 98304;       // (unused)
constexpr size_t OFF_MPREH = OFF_E0H   + 8388608;     // f16 [65536][256]

__device__ __forceinline__ float sigmoidf_(float x) { return 1.0f / (1.0f + expf(-x)); }

__device__ __forceinline__ f16x8 cvtp(f32x4 a, f32x4 b) {
  union { h16x2 q[4]; f16x8 h; } u;
  u.q[0] = __builtin_amdgcn_cvt_pkrtz(a[0], a[1]);
  u.q[1] = __builtin_amdgcn_cvt_pkrtz(a[2], a[3]);
  u.q[2] = __builtin_amdgcn_cvt_pkrtz(b[0], b[1]);
  u.q[3] = __builtin_amdgcn_cvt_pkrtz(b[2], b[3]);
  return u.h;
}

__device__ __forceinline__ f16x4 cvtp4(const float4& g) {
  union { h16x2 q[2]; f16x4 h; } u;
  u.q[0] = __builtin_amdgcn_cvt_pkrtz(g.x, g.y);
  u.q[1] = __builtin_amdgcn_cvt_pkrtz(g.z, g.w);
  return u.h;
}

// ---------------------------------------------------------------------------
// cast_all: prefragment all weight matrices into f16 MFMA-B layout
// ---------------------------------------------------------------------------
__global__ __launch_bounds__(256) void cast_all(
    const float* __restrict__ W_er, const float* __restrict__ W_nr,
    const float* __restrict__ Wm,   const float* __restrict__ Wl1,
    const float* __restrict__ Wi,   const float* __restrict__ Wh,
    const float* __restrict__ Wro,
    f16* __restrict__ Wer8, f16* __restrict__ Wnr8, f16* __restrict__ Wev8,
    f16* __restrict__ Whw8, f16* __restrict__ Wl18, f16* __restrict__ Wi8,
    f16* __restrict__ Wh8,  f16* __restrict__ Wro8)
{
  int b = blockIdx.x, t = threadIdx.x;
  const float* W; f16* out; int ldw, koff, K, N, Npad, kc, nb;
  if (b < 152)      { W=W_er; out=Wer8; ldw=FE;  koff=0;   K=FE;  N=256; Npad=256; kc=b;     nb=0; }
  else if (b < 296) { b-=152; W=W_nr; out=Wnr8; ldw=FN;  koff=0;   K=FN;  N=256; Npad=256; kc=b; nb=0; }
  else if (b < 328) { b-=296; W=Wm;   out=Wev8; ldw=512; koff=256; K=256; N=256; Npad=256; kc=b; nb=0; }
  else if (b < 360) { b-=328; W=Wm;   out=Whw8; ldw=512; koff=0;   K=256; N=256; Npad=256; kc=b; nb=0; }
  else if (b < 392) { b-=360; W=Wl1;  out=Wl18; ldw=256; koff=0;   K=256; N=256; Npad=256; kc=b; nb=0; }
  else if (b < 488) { b-=392; W=Wi;   out=Wi8;  ldw=256; koff=0;   K=256; N=768; Npad=768; kc=b&31; nb=(b>>5)*256; }
  else if (b < 584) { b-=488; W=Wh;   out=Wh8;  ldw=256; koff=0;   K=256; N=768; Npad=768; kc=b&31; nb=(b>>5)*256; }
  else              { b-=584; W=Wro;  out=Wro8; ldw=256; koff=0;   K=256; N=600; Npad=768; kc=b&31; nb=(b>>5)*256; }
  int n = nb + t;
  if (n >= Npad) return;
  f16x8 h;
#pragma unroll
  for (int j = 0; j < 8; ++j) {
    int k = kc * 8 + j;
    float v = (k < K && n < N) ? W[(size_t)n * ldw + koff + k] : 0.0f;
    h[j] = (f16)v;
  }
  *reinterpret_cast<f16x8*>(out + ((size_t)kc * Npad + n) * 8) = h;
}

// ---------------------------------------------------------------------------
// Fused E0 + score-1 + Mpre.  E0 phase: direct-to-register A loads
// (no LDS staging, no barriers, no DMA FIFO) — per (m,ks) load pair covers
// 16 rows x 128B = full cache lines; 4 waves share the A slice via L1.
// Then E0 tile -> LDS T (swizzled); S pass; M pass; Mpre out.
// ---------------------------------------------------------------------------
__global__ __launch_bounds__(256) void e0_sm(
    const float* __restrict__ A, const f16* __restrict__ Ber,
    const float* __restrict__ b_er,
    const f16* __restrict__ Bl1, const f16* __restrict__ Bev,
    const float* __restrict__ bl1, const float* __restrict__ Wl2,
    const float* __restrict__ bl2,
    const float* __restrict__ XpH, const float* __restrict__ bm,
    float* __restrict__ S1, f16* __restrict__ Mpreh)
{
  const int tid = threadIdx.x;
  const int wave = tid >> 6, l = tid & 63;
  const int lo = l & 15, hi = l >> 4;
  const int wcol = wave * 64;
  alignas(16) __shared__ char sm[32768];     // T tile (also Mpre repack)
  __shared__ float red[64][4];
  const size_t arow0 = (size_t)blockIdx.x * 64;

  // ---------------- phase E0: direct-to-reg K-loop ----------------
  {
    f32x4 acc[4][4] = {};
    const char* abase[4];
#pragma unroll
    for (int m = 0; m < 4; ++m)
      abase[m] = (const char*)(A + (arow0 + m*16 + lo) * FE) + hi*32;

    for (int t = 0; t < 19; ++t) {
#pragma unroll
      for (int ks = 0; ks < 2; ++ks) {
        const int kc = t*8 + ks*4 + hi;
        f16x8 af[4], bf[4];
#pragma unroll
        for (int m = 0; m < 4; ++m) {
          const char* p = abase[m] + t*256 + ks*128;
          f32x4 a0 = *reinterpret_cast<const f32x4*>(p);
          f32x4 a1 = *reinterpret_cast<const f32x4*>(p + 16);
          af[m] = cvtp(a0, a1);
        }
#pragma unroll
        for (int n = 0; n < 4; ++n)
          bf[n] = *reinterpret_cast<const f16x8*>(Ber + ((size_t)kc*256 + (wcol + n*16 + lo)) * 8);
#pragma unroll
        for (int m = 0; m < 4; ++m)
#pragma unroll
          for (int n = 0; n < 4; ++n)
            acc[m][n] = __builtin_amdgcn_mfma_f32_16x16x32_f16(af[m], bf[n], acc[m][n], 0, 0, 0);
      }
    }

    // E0 tile -> T (f16, swizzled 512B rows); per-wave column ranges disjoint
#pragma unroll
    for (int m = 0; m < 4; ++m)
#pragma unroll
      for (int n = 0; n < 4; ++n) {
        const int col = wcol + n*16 + lo;
        const float bb = b_er[col];
#pragma unroll
        for (int r = 0; r < 4; ++r) {
          const int rl = m*16 + hi*4 + r;
          const int byte = rl*512 + ((col*2) ^ ((rl & 7) << 4));
          *reinterpret_cast<f16*>(sm + byte) = (f16)(acc[m][n][r] + bb);
        }
      }
  }
  __syncthreads();

  // ---------------- pass S: accS = T @ Wl1^T ----------------
  {
    f32x4 accS[4][4] = {};
    for (int t = 0; t < 4; ++t) {
#pragma unroll
      for (int ks = 0; ks < 2; ++ks) {
        const int kc = t*8 + ks*4 + hi;
        const int b0 = t*128 + ks*64 + hi*16;
        f16x8 af[4], bf[4];
#pragma unroll
        for (int m = 0; m < 4; ++m) {
          const int r = m*16 + lo;
          af[m] = *reinterpret_cast<const f16x8*>(sm + r*512 + (b0 ^ ((r & 7) << 4)));
        }
#pragma unroll
        for (int n = 0; n < 4; ++n)
          bf[n] = *reinterpret_cast<const f16x8*>(Bl1 + ((size_t)kc*256 + (wcol + n*16 + lo)) * 8);
#pragma unroll
        for (int m = 0; m < 4; ++m)
#pragma unroll
          for (int n = 0; n < 4; ++n)
            accS[m][n] = __builtin_amdgcn_mfma_f32_16x16x32_f16(af[m], bf[n], accS[m][n], 0, 0, 0);
      }
    }
#pragma unroll
    for (int m = 0; m < 4; ++m) {
#pragma unroll
      for (int r = 0; r < 4; ++r) {
        float p = 0.f;
#pragma unroll
        for (int n = 0; n < 4; ++n) {
          const int col = wcol + n*16 + lo;
          p += Wl2[col] * fmaxf(accS[m][n][r] + bl1[col], 0.0f);
        }
        p += __shfl_xor(p, 1); p += __shfl_xor(p, 2);
        p += __shfl_xor(p, 4); p += __shfl_xor(p, 8);
        if (lo == 0) red[m*16 + hi*4 + r][wave] = p;
      }
    }
  }

  // ---------------- pass M: accM = T @ Wev^T ----------------
  {
    f32x4 accM[4][4] = {};
    for (int t = 0; t < 4; ++t) {
#pragma unroll
      for (int ks = 0; ks < 2; ++ks) {
        const int kc = t*8 + ks*4 + hi;
        const int b0 = t*128 + ks*64 + hi*16;
        f16x8 af[4], bf[4];
#pragma unroll
        for (int m = 0; m < 4; ++m) {
          const int r = m*16 + lo;
          af[m] = *reinterpret_cast<const f16x8*>(sm + r*512 + (b0 ^ ((r & 7) << 4)));
        }
#pragma unroll
        for (int n = 0; n < 4; ++n)
          bf[n] = *reinterpret_cast<const f16x8*>(Bev + ((size_t)kc*256 + (wcol + n*16 + lo)) * 8);
#pragma unroll
        for (int m = 0; m < 4; ++m)
#pragma unroll
          for (int n = 0; n < 4; ++n)
            accM[m][n] = __builtin_amdgcn_mfma_f32_16x16x32_f16(af[m], bf[n], accM[m][n], 0, 0, 0);
      }
    }
    __syncthreads();   // all T reads done; safe to overwrite with Mpre (linear)
    const int rxb = (blockIdx.x >> 6) * 64;
#pragma unroll
    for (int m = 0; m < 4; ++m)
#pragma unroll
      for (int n = 0; n < 4; ++n) {
        const int col = wcol + n*16 + lo;
        const float bb = bm[col];
#pragma unroll
        for (int r = 0; r < 4; ++r) {
          const int rl = m*16 + hi*4 + r;
          float v = accM[m][n][r] + XpH[(size_t)(rxb + rl)*256 + col] + bb;
          *reinterpret_cast<f16*>(sm + rl*512 + col*2) = (f16)fmaxf(v, 0.0f);
        }
      }
  }
  __syncthreads();
#pragma unroll
  for (int i = 0; i < 8; ++i) {
    const int lin = i*4096 + tid*16;
    f16x8 v = *reinterpret_cast<const f16x8*>(sm + lin);
    *reinterpret_cast<f16x8*>((char*)Mpreh + arow0*512 + lin) = v;
  }
  if (tid < 64)
    S1[arow0 + tid] = sigmoidf_(bl2[0] + red[tid][0] + red[tid][1] + red[tid][2] + red[tid][3]);
}

// ---------------------------------------------------------------------------
// Score pass 2 (transposed gather, reg-staged) + fused msum.
// ---------------------------------------------------------------------------
__global__ __launch_bounds__(256) void attn2_ms(
    const f16* __restrict__ Mpreh, const float* __restrict__ S1,
    const f16* __restrict__ Bl1, const float* __restrict__ bl1,
    const float* __restrict__ Wl2, const float* __restrict__ bl2,
    float* __restrict__ adj, f16* __restrict__ xf)
{
  const int blk = blockIdx.x;
  const int b = blk >> 6, v = blk & 63;
  const int tid = threadIdx.x;
  const int wave = tid >> 6, l = tid & 63;
  const int lo = l & 15, hi = l >> 4;
  const int wcol = wave * 64;
  __shared__ f16 As[2][64][72];
  __shared__ float red[64][4];
  __shared__ float s1s[64];
  __shared__ float s2s[64];
  f32x4 acc[4][4] = {};
  const int rr0 = tid >> 3, part = tid & 7;
  const size_t pbase = (size_t)b * 4096 + v;
  f16x8 ga, gb;

  if (tid < 64) s1s[tid] = S1[pbase + (size_t)tid * 64];
  __syncthreads();

#define A2_LOAD(T)                                                              \
  { ga = *reinterpret_cast<const f16x8*>(Mpreh + (pbase + (size_t)rr0*64)*256 + (T)*64 + part*8);     \
    gb = *reinterpret_cast<const f16x8*>(Mpreh + (pbase + (size_t)(rr0+32)*64)*256 + (T)*64 + part*8); }
#define A2_WRITE(BUF)                                                           \
  { f16 sa = (f16)s1s[rr0], sb = (f16)s1s[rr0 + 32];                            \
    f16x8 ha = ga, hb = gb;                                                     \
    _Pragma("unroll") for (int j = 0; j < 8; ++j) { ha[j] *= sa; hb[j] *= sb; } \
    *reinterpret_cast<f16x8*>(&As[BUF][rr0][part*8]) = ha;                      \
    *reinterpret_cast<f16x8*>(&As[BUF][rr0 + 32][part*8]) = hb; }

  A2_LOAD(0); A2_WRITE(0);
  for (int t = 0; t < 4; ++t) {
    __syncthreads();
    if (t < 3) A2_LOAD(t + 1);
    const int cur = t & 1;
#pragma unroll
    for (int ks = 0; ks < 2; ++ks) {
      f16x8 af[4], bf[4];
      const int kc = t*8 + ks*4 + hi;
#pragma unroll
      for (int m = 0; m < 4; ++m)
        af[m] = *reinterpret_cast<const f16x8*>(&As[cur][m*16 + lo][ks*32 + hi*8]);
#pragma unroll
      for (int n = 0; n < 4; ++n)
        bf[n] = *reinterpret_cast<const f16x8*>(Bl1 + ((size_t)kc*256 + (wcol + n*16 + lo)) * 8);
#pragma unroll
      for (int m = 0; m < 4; ++m)
#pragma unroll
        for (int n = 0; n < 4; ++n)
          acc[m][n] = __builtin_amdgcn_mfma_f32_16x16x32_f16(af[m], bf[n], acc[m][n], 0, 0, 0);
    }
    if (t < 3) A2_WRITE(cur ^ 1);
  }
#undef A2_LOAD
#undef A2_WRITE
#pragma unroll
  for (int m = 0; m < 4; ++m) {
#pragma unroll
    for (int r = 0; r < 4; ++r) {
      float p = 0.f;
#pragma unroll
      for (int n = 0; n < 4; ++n) {
        const int col = wcol + n*16 + lo;
        p += Wl2[col] * fmaxf(acc[m][n][r] + bl1[col], 0.0f);
      }
      p += __shfl_xor(p, 1); p += __shfl_xor(p, 2);
      p += __shfl_xor(p, 4); p += __shfl_xor(p, 8);
      if (lo == 0) red[m*16 + hi*4 + r][wave] = p;
    }
  }
  __syncthreads();
  if (tid < 64) {
    float s = bl2[0] + red[tid][0] + red[tid][1] + red[tid][2] + red[tid][3];
    adj[(size_t)b*4096 + (size_t)v*64 + tid] = s;
    s2s[tid] = sigmoidf_(s);
  }
  __syncthreads();
  const int c = tid;
  const f16* mp = Mpreh + (size_t)blk * 64 * 256 + c;
  float accx = 0.f;
#pragma unroll 8
  for (int w = 0; w < 64; ++w)
    accx += (float)mp[(size_t)w * 256] * s2s[w];
  xf[(size_t)blk * 256 + c] = (f16)accx;
}

// ---------------------------------------------------------------------------
// Fused Xp + XpH, BM=16, grid 64
// ---------------------------------------------------------------------------
__global__ __launch_bounds__(256) void xp_xph16(
    const float* __restrict__ A, const f16* __restrict__ Bnr,
    const float* __restrict__ b_nr, const f16* __restrict__ Bhw,
    float* __restrict__ Xp, f16* __restrict__ Xpf, float* __restrict__ XpH)
{
  const int tid = threadIdx.x;
  const int wave = tid >> 6, l = tid & 63;
  const int lo = l & 15, hi = l >> 4;
  const int wcol = wave * 64;
  __shared__ f16 As[2][16][72];
  __shared__ f16 XpS[16][264];
  f32x4 acc[4] = {};
  const size_t arow0 = (size_t)blockIdx.x * 16;
  const int srow = tid >> 4, spart = tid & 15;
  const float* abase = A + (arow0 + srow) * FN;
  float4 g;
  const float4 z4 = make_float4(0.f, 0.f, 0.f, 0.f);

#define XQ_LOAD(T)                                                          \
  { int kb = (T)*64 + spart*4;                                              \
    g = (kb + 4 <= FN) ? *(const float4*)(abase + kb) : z4; }
#define XQ_WRITE(BUF)                                                       \
  { *reinterpret_cast<f16x4*>(&As[BUF][srow][spart*4]) = cvtp4(g); }

  XQ_LOAD(0); XQ_WRITE(0);
  for (int t = 0; t < 18; ++t) {
    __syncthreads();
    if (t < 17) XQ_LOAD(t + 1);
    const int cur = t & 1;
#pragma unroll
    for (int ks = 0; ks < 2; ++ks) {
      const int kc = t*8 + ks*4 + hi;
      f16x8 af = *reinterpret_cast<const f16x8*>(&As[cur][lo][ks*32 + hi*8]);
      f16x8 bf[4];
#pragma unroll
      for (int n = 0; n < 4; ++n)
        bf[n] = *reinterpret_cast<const f16x8*>(Bnr + ((size_t)kc*256 + (wcol + n*16 + lo)) * 8);
#pragma unroll
      for (int n = 0; n < 4; ++n)
        acc[n] = __builtin_amdgcn_mfma_f32_16x16x32_f16(af, bf[n], acc[n], 0, 0, 0);
    }
    if (t < 17) XQ_WRITE(cur ^ 1);
  }
#undef XQ_LOAD
#undef XQ_WRITE
#pragma unroll
  for (int n = 0; n < 4; ++n) {
    const int col = wcol + n*16 + lo;
    const float bb = b_nr[col];
#pragma unroll
    for (int r = 0; r < 4; ++r) {
      const size_t row = arow0 + hi*4 + r;
      float v = acc[n][r] + bb;
      Xp[row * 256 + col] = v;
      f16 hv = (f16)v;
      Xpf[row * 256 + col] = hv;
      XpS[hi*4 + r][col] = hv;
    }
  }
  __syncthreads();
  f32x4 acch[4] = {};
  for (int t = 0; t < 4; ++t) {
#pragma unroll
    for (int ks = 0; ks < 2; ++ks) {
      const int kc = t*8 + ks*4 + hi;
      f16x8 af = *reinterpret_cast<const f16x8*>(&XpS[lo][t*64 + ks*32 + hi*8]);
      f16x8 bf[4];
#pragma unroll
      for (int n = 0; n < 4; ++n)
        bf[n] = *reinterpret_cast<const f16x8*>(Bhw + ((size_t)kc*256 + (wcol + n*16 + lo)) * 8);
#pragma unroll
      for (int n = 0; n < 4; ++n)
        acch[n] = __builtin_amdgcn_mfma_f32_16x16x32_f16(af, bf[n], acch[n], 0, 0, 0);
    }
  }
#pragma unroll
  for (int n = 0; n < 4; ++n) {
    const int col = wcol + n*16 + lo;
#pragma unroll
    for (int r = 0; r < 4; ++r)
      XpH[(arow0 + hi*4 + r) * 256 + col] = acch[n][r];
  }
}

// ---------------------------------------------------------------------------
// Merged gi/gh GEMM, BM=16: grid (64, 6)
// ---------------------------------------------------------------------------
__global__ __launch_bounds__(256) void gigh16(
    const f16* __restrict__ xf, const f16* __restrict__ Xpf,
    const f16* __restrict__ Wi8, const f16* __restrict__ Wh8,
    const float* __restrict__ bi, const float* __restrict__ bh,
    float* __restrict__ gi, float* __restrict__ gh)
{
  const int rb = blockIdx.x;
  int cb = blockIdx.y;
  const f16* A; const f16* Bp; const float* bias; float* C;
  if (cb < 3) { A = xf;  Bp = Wi8; bias = bi; C = gi; }
  else        { A = Xpf; Bp = Wh8; bias = bh; C = gh; cb -= 3; }
  const int tid = threadIdx.x;
  const int wave = tid >> 6, l = tid & 63;
  const int lo = l & 15, hi = l >> 4;
  const int wcol = cb * 256 + wave * 64;
  __shared__ f16 As[16][264];
  f32x4 acc[4] = {};
  const size_t arow0 = (size_t)rb * 16;

#pragma unroll
  for (int i = 0; i < 2; ++i) {
    int idx = i * 256 + tid;
    int rr = idx >> 5, part = idx & 31;
    *reinterpret_cast<f16x8*>(&As[rr][part*8]) =
        *reinterpret_cast<const f16x8*>(A + (arow0 + rr)*256 + part*8);
  }
  __syncthreads();

  for (int t = 0; t < 4; ++t) {
#pragma unroll
    for (int ks = 0; ks < 2; ++ks) {
      const int kc = t*8 + ks*4 + hi;
      f16x8 af = *reinterpret_cast<const f16x8*>(&As[lo][t*64 + ks*32 + hi*8]);
      f16x8 bf[4];
#pragma unroll
      for (int n = 0; n < 4; ++n)
        bf[n] = *reinterpret_cast<const f16x8*>(Bp + ((size_t)kc*768 + (wcol + n*16 + lo)) * 8);
#pragma unroll
      for (int n = 0; n < 4; ++n)
        acc[n] = __builtin_amdgcn_mfma_f32_16x16x32_f16(af, bf[n], acc[n], 0, 0, 0);
    }
  }
#pragma unroll
  for (int n = 0; n < 4; ++n) {
    const int col = wcol + n*16 + lo;
    const float bb = bias[col];
#pragma unroll
    for (int r = 0; r < 4; ++r)
      C[(arow0 + hi*4 + r) * 768 + col] = acc[n][r] + bb;
  }
}

// ---------------------------------------------------------------------------
// Labels GEMM with GRU fused into staging, BM=16: grid (64, 3)
// ---------------------------------------------------------------------------
__global__ __launch_bounds__(256) void labels_gru16(
    const float* __restrict__ gi, const float* __restrict__ gh,
    const float* __restrict__ Xp, const f16* __restrict__ Wro8,
    const float* __restrict__ bro, float* __restrict__ labels)
{
  const int rb = blockIdx.x, cb = blockIdx.y;
  const int tid = threadIdx.x;
  const int wave = tid >> 6, l = tid & 63;
  const int lo = l & 15, hi = l >> 4;
  const int wcol = cb * 256 + wave * 64;
  __shared__ f16 As[16][264];
  f32x4 acc[4] = {};
  const size_t arow0 = (size_t)rb * 16;

  {
    const int rr = tid >> 4, c0 = (tid & 15) * 16;
    const float* gir = gi + (arow0 + rr) * 768;
    const float* ghr = gh + (arow0 + rr) * 768;
    const float* xpr = Xp + (arow0 + rr) * 256;
#pragma unroll
    for (int j = 0; j < 16; ++j) {
      const int c = c0 + j;
      float r = sigmoidf_(gir[c] + ghr[c]);
      float z = sigmoidf_(gir[256 + c] + ghr[256 + c]);
      float n = tanhf(gir[512 + c] + r * ghr[512 + c]);
      float h = xpr[c];
      As[rr][c] = (f16)((1.0f - z) * n + z * h);
    }
  }
  __syncthreads();

  for (int t = 0; t < 4; ++t) {
#pragma unroll
    for (int ks = 0; ks < 2; ++ks) {
      const int kc = t*8 + ks*4 + hi;
      f16x8 af = *reinterpret_cast<const f16x8*>(&As[lo][t*64 + ks*32 + hi*8]);
      f16x8 bf[4];
#pragma unroll
      for (int n = 0; n < 4; ++n)
        bf[n] = *reinterpret_cast<const f16x8*>(Wro8 + ((size_t)kc*768 + (wcol + n*16 + lo)) * 8);
#pragma unroll
      for (int n = 0; n < 4; ++n)
        acc[n] = __builtin_amdgcn_mfma_f32_16x16x32_f16(af, bf[n], acc[n], 0, 0, 0);
    }
  }
#pragma unroll
  for (int n = 0; n < 4; ++n) {
    const int col = wcol + n*16 + lo;
    if (col < KC) {
      const float bb = bro[col];
#pragma unroll
      for (int r = 0; r < 4; ++r)
        labels[(arow0 + hi*4 + r) * (size_t)KC + col] = acc[n][r] + bb;
    }
  }
}

} // namespace

extern "C" void kernel_launch(void* const* d_in, const int* in_sizes, int n_in,
                              void* d_out, int out_size, void* d_ws, size_t ws_size,
                              hipStream_t stream)
{
  const float* ef   = (const float*)d_in[0];
  const float* nf   = (const float*)d_in[1];
  const float* W_er = (const float*)d_in[7];
  const float* b_er = (const float*)d_in[8];
  const float* W_nr = (const float*)d_in[9];
  const float* b_nr = (const float*)d_in[10];
  const float* Wl1  = (const float*)d_in[11];
  const float* bl1  = (const float*)d_in[12];
  const float* Wl2  = (const float*)d_in[13];
  const float* bl2  = (const float*)d_in[14];
  const float* Wm   = (const float*)d_in[15];
  const float* bm   = (const float*)d_in[16];
  const float* Wi   = (const float*)d_in[17];
  const float* bi   = (const float*)d_in[18];
  const float* Wh   = (const float*)d_in[19];
  const float* bh   = (const float*)d_in[20];
  const float* Wro  = (const float*)d_in[21];
  const float* bro  = (const float*)d_in[22];

  float* ws = (float*)d_ws;
  float* Xp    = ws + OFF_XP;
  f16*   Xpf   = (f16*)(ws + OFF_XPF);
  float* XpH   = ws + OFF_XPH;
  float* S1    = ws + OFF_S1;
  f16*   xf    = (f16*)(ws + OFF_XF);
  float* gi    = ws + OFF_GI;
  float* gh    = ws + OFF_GH;
  f16*   Wer8  = (f16*)(ws + OFF_WER8);
  f16*   Wnr8  = (f16*)(ws + OFF_WNR8);
  f16*   Wev8  = (f16*)(ws + OFF_WEV8);
  f16*   Whw8  = (f16*)(ws + OFF_WHW8);
  f16*   Wl18  = (f16*)(ws + OFF_WL18);
  f16*   Wi8   = (f16*)(ws + OFF_WI8);
  f16*   Wh8   = (f16*)(ws + OFF_WH8);
  f16*   Wro8  = (f16*)(ws + OFF_WRO8);
  f16*   Mpreh = (f16*)(ws + OFF_MPREH);
  float* adj    = (float*)d_out;
  float* labels = (float*)d_out + PAIRS;

  dim3 blk(256);

  cast_all<<<dim3(680), blk, 0, stream>>>(W_er, W_nr, Wm, Wl1, Wi, Wh, Wro,
                                          Wer8, Wnr8, Wev8, Whw8, Wl18, Wi8, Wh8, Wro8);
  xp_xph16<<<dim3(64), blk, 0, stream>>>(nf, Wnr8, b_nr, Whw8, Xp, Xpf, XpH);
  e0_sm<<<dim3(PAIRS / 64), blk, 0, stream>>>(ef, Wer8, b_er, Wl18, Wev8,
                                              bl1, Wl2, bl2, XpH, bm,
                                              S1, Mpreh);
  attn2_ms<<<dim3(PAIRS / 64), blk, 0, stream>>>(Mpreh, S1, Wl18, bl1, Wl2, bl2,
                                                 adj, xf);
  gigh16<<<dim3(64, 6), blk, 0, stream>>>(xf, Xpf, Wi8, Wh8, bi, bh, gi, gh);
  labels_gru16<<<dim3(64, 3), blk, 0, stream>>>(gi, gh, Xp, Wro8, bro, labels);
}

// Round 12
// 225.828 us; speedup vs baseline: 1.4029x; 1.4029x over previous
//
#include <hip/hip_runtime.h>
#include <cmath>

namespace {

using f16 = _Float16;
typedef f16 f16x8 __attribute__((ext_vector_type(8)));
typedef f16 f16x4 __attribute__((ext_vector_type(4)));
typedef __fp16 h16x2 __attribute__((ext_vector_type(2)));
typedef float f32x4 __attribute__((ext_vector_type(4)));

constexpr int FE = 1216, FN = 1108, MD = 256, KC = 600;
constexpr int PAIRS = 65536, ROWS = 1024;

// workspace offsets (float units, all 16B-aligned)
constexpr size_t OFF_XP    = 0;                       // fp32 [1024][256]
constexpr size_t OFF_XPF   = OFF_XP    + 262144;      // f16  [1024][256]
constexpr size_t OFF_XPH   = OFF_XPF   + 131072;      // fp32 [1024][256]
constexpr size_t OFF_S1    = OFF_XPH   + 262144;      // fp32 [65536]
constexpr size_t OFF_S2    = OFF_S1    + 65536;       // (unused)
constexpr size_t OFF_XF    = OFF_S2    + 65536;       // f16  [1024][256]
constexpr size_t OFF_GI    = OFF_XF    + 131072;      // fp32 [1024][768]
constexpr size_t OFF_GH    = OFF_GI    + 786432;      // fp32 [1024][768]
constexpr size_t OFF_HNF   = OFF_GH    + 786432;      // (unused)
constexpr size_t OFF_WER8  = OFF_HNF   + 131072;      // f16 prefrag 152*256*8
constexpr size_t OFF_WNR8  = OFF_WER8  + 155648;      // 144*256*8
constexpr size_t OFF_WEV8  = OFF_WNR8  + 147456;      // 32*256*8
constexpr size_t OFF_WHW8  = OFF_WEV8  + 32768;       // 32*256*8
constexpr size_t OFF_WL18  = OFF_WHW8  + 32768;       // 32*256*8
constexpr size_t OFF_WI8   = OFF_WL18  + 32768;       // 32*768*8
constexpr size_t OFF_WH8   = OFF_WI8   + 98304;       // 32*768*8
constexpr size_t OFF_WRO8  = OFF_WH8   + 98304;       // 32*768*8 (KC pad 768)
constexpr size_t OFF_E0H   = OFF_WRO8  + 98304;       // (unused)
constexpr size_t OFF_MPREH = OFF_E0H   + 8388608;     // f16 [65536][256]

__device__ __forceinline__ float sigmoidf_(float x) { return 1.0f / (1.0f + expf(-x)); }

__device__ __forceinline__ void dma16(const void* g, void* l) {
  __builtin_amdgcn_global_load_lds((const unsigned int*)g, (unsigned int*)l, 16, 0, 0);
}

__device__ __forceinline__ f16x8 cvtp(f32x4 a, f32x4 b) {
  union { h16x2 q[4]; f16x8 h; } u;
  u.q[0] = __builtin_amdgcn_cvt_pkrtz(a[0], a[1]);
  u.q[1] = __builtin_amdgcn_cvt_pkrtz(a[2], a[3]);
  u.q[2] = __builtin_amdgcn_cvt_pkrtz(b[0], b[1]);
  u.q[3] = __builtin_amdgcn_cvt_pkrtz(b[2], b[3]);
  return u.h;
}

__device__ __forceinline__ f16x4 cvtp4(const float4& g) {
  union { h16x2 q[2]; f16x4 h; } u;
  u.q[0] = __builtin_amdgcn_cvt_pkrtz(g.x, g.y);
  u.q[1] = __builtin_amdgcn_cvt_pkrtz(g.z, g.w);
  return u.h;
}

// ---------------------------------------------------------------------------
// cast_all: prefragment all weight matrices into f16 MFMA-B layout
// ---------------------------------------------------------------------------
__global__ __launch_bounds__(256) void cast_all(
    const float* __restrict__ W_er, const float* __restrict__ W_nr,
    const float* __restrict__ Wm,   const float* __restrict__ Wl1,
    const float* __restrict__ Wi,   const float* __restrict__ Wh,
    const float* __restrict__ Wro,
    f16* __restrict__ Wer8, f16* __restrict__ Wnr8, f16* __restrict__ Wev8,
    f16* __restrict__ Whw8, f16* __restrict__ Wl18, f16* __restrict__ Wi8,
    f16* __restrict__ Wh8,  f16* __restrict__ Wro8)
{
  int b = blockIdx.x, t = threadIdx.x;
  const float* W; f16* out; int ldw, koff, K, N, Npad, kc, nb;
  if (b < 152)      { W=W_er; out=Wer8; ldw=FE;  koff=0;   K=FE;  N=256; Npad=256; kc=b;     nb=0; }
  else if (b < 296) { b-=152; W=W_nr; out=Wnr8; ldw=FN;  koff=0;   K=FN;  N=256; Npad=256; kc=b; nb=0; }
  else if (b < 328) { b-=296; W=Wm;   out=Wev8; ldw=512; koff=256; K=256; N=256; Npad=256; kc=b; nb=0; }
  else if (b < 360) { b-=328; W=Wm;   out=Whw8; ldw=512; koff=0;   K=256; N=256; Npad=256; kc=b; nb=0; }
  else if (b < 392) { b-=360; W=Wl1;  out=Wl18; ldw=256; koff=0;   K=256; N=256; Npad=256; kc=b; nb=0; }
  else if (b < 488) { b-=392; W=Wi;   out=Wi8;  ldw=256; koff=0;   K=256; N=768; Npad=768; kc=b&31; nb=(b>>5)*256; }
  else if (b < 584) { b-=488; W=Wh;   out=Wh8;  ldw=256; koff=0;   K=256; N=768; Npad=768; kc=b&31; nb=(b>>5)*256; }
  else              { b-=584; W=Wro;  out=Wro8; ldw=256; koff=0;   K=256; N=600; Npad=768; kc=b&31; nb=(b>>5)*256; }
  int n = nb + t;
  if (n >= Npad) return;
  f16x8 h;
#pragma unroll
  for (int j = 0; j < 8; ++j) {
    int k = kc * 8 + j;
    float v = (k < K && n < N) ? W[(size_t)n * ldw + koff + k] : 0.0f;
    h[j] = (f16)v;
  }
  *reinterpret_cast<f16x8*>(out + ((size_t)kc * Npad + n) * 8) = h;
}

// ---------------------------------------------------------------------------
// Fused E0 + score-1 + Mpre.  E0 phase: BK=32 chunks, BOTH A and B staged via
// global_load_lds into a 3-deep LDS pipeline. No vector loads in the K-loop
// -> vmcnt FIFO holds only DMAs -> exact counted waits, 48KB/block in flight.
//   per iter: wait vmcnt(6); barrier; issue chunk t+2 (6 DMAs); compute t.
// Then E0 tile -> LDS T (swizzled); S pass; M pass; Mpre out (round-10 code).
// ---------------------------------------------------------------------------
__global__ __launch_bounds__(256) void e0_sm(
    const float* __restrict__ A, const f16* __restrict__ Ber,
    const float* __restrict__ b_er,
    const f16* __restrict__ Bl1, const f16* __restrict__ Bev,
    const float* __restrict__ bl1, const float* __restrict__ Wl2,
    const float* __restrict__ bl2,
    const float* __restrict__ XpH, const float* __restrict__ bm,
    float* __restrict__ S1, f16* __restrict__ Mpreh)
{
  const int tid = threadIdx.x;
  const int wave = tid >> 6, l = tid & 63;
  const int lo = l & 15, hi = l >> 4;
  const int wcol = wave * 64;
  alignas(16) __shared__ char sm[73728];   // 3 x (8KB A + 16KB B); T reuses
  __shared__ float red[64][4];
  const size_t arow0 = (size_t)blockIdx.x * 64;

  // ---------------- phase E0 ----------------
  {
    f32x4 acc[4][4] = {};
    // A DMA sources (2/wave): dest lin = wave*2048 + j*1024 + l*16
    // row = wave*16 + j*8 + (l>>3); phys slot (l&7) holds src slot (l&7)^(row&7)
    const char* asrc[2]; int adst[2];
    // B DMA sources (4/wave): dest lin = 8192 + wave*4096 + j*1024 + l*16
    // kc_local = wave; phys col c holds src col c ^ wave
    const char* bsrc[4]; int bdst[4];
#pragma unroll
    for (int j = 0; j < 2; ++j) {
      const int row = wave*16 + j*8 + (l >> 3);
      const int slot = (l & 7) ^ (row & 7);
      asrc[j] = (const char*)(A + (arow0 + row) * FE + slot * 4);
      adst[j] = wave*2048 + j*1024 + l*16;
    }
#pragma unroll
    for (int j = 0; j < 4; ++j) {
      const int c = j*64 + l;
      bsrc[j] = (const char*)(Ber + ((size_t)wave*256 + (c ^ wave)) * 8);
      bdst[j] = 8192 + wave*4096 + j*1024 + l*16;
    }

#define CH_ISSUE(P)                                                           \
    { char* bb = sm + (P)*24576;                                              \
      dma16(asrc[0], bb + adst[0]); asrc[0] += 128;                           \
      dma16(asrc[1], bb + adst[1]); asrc[1] += 128;                           \
      dma16(bsrc[0], bb + bdst[0]); bsrc[0] += 16384;                         \
      dma16(bsrc[1], bb + bdst[1]); bsrc[1] += 16384;                         \
      dma16(bsrc[2], bb + bdst[2]); bsrc[2] += 16384;                         \
      dma16(bsrc[3], bb + bdst[3]); bsrc[3] += 16384; }

    CH_ISSUE(0)
    CH_ISSUE(1)

    for (int t = 0; t < 38; ++t) {
      if (t < 37) { asm volatile("s_waitcnt vmcnt(6)" ::: "memory"); }
      else        { asm volatile("s_waitcnt vmcnt(0)" ::: "memory"); }
      __builtin_amdgcn_sched_barrier(0);
      __builtin_amdgcn_s_barrier();
      __builtin_amdgcn_sched_barrier(0);
      if (t < 36) { CH_ISSUE((t + 2) % 3) }
      __builtin_amdgcn_sched_barrier(0);

      const char* Ab = sm + (t % 3) * 24576;
      const char* Bb = Ab + 8192;
      f16x8 af[4], bf[4];
#pragma unroll
      for (int m = 0; m < 4; ++m) {
        const int r = m*16 + lo;
        const int s0 = (2*hi)     ^ (r & 7);
        const int s1 = (2*hi + 1) ^ (r & 7);
        f32x4 a0 = *reinterpret_cast<const f32x4*>(Ab + r*128 + s0*16);
        f32x4 a1 = *reinterpret_cast<const f32x4*>(Ab + r*128 + s1*16);
        af[m] = cvtp(a0, a1);
      }
#pragma unroll
      for (int n = 0; n < 4; ++n) {
        const int col = wcol + n*16 + lo;
        bf[n] = *reinterpret_cast<const f16x8*>(Bb + hi*4096 + (col ^ hi)*16);
      }
#pragma unroll
      for (int m = 0; m < 4; ++m)
#pragma unroll
        for (int n = 0; n < 4; ++n)
          acc[m][n] = __builtin_amdgcn_mfma_f32_16x16x32_f16(af[m], bf[n], acc[m][n], 0, 0, 0);
    }
#undef CH_ISSUE

    __syncthreads();     // all reads done; stage region dead -> reuse as T
    // E0 tile -> T (f16, swizzled 512B rows)
#pragma unroll
    for (int m = 0; m < 4; ++m)
#pragma unroll
      for (int n = 0; n < 4; ++n) {
        const int col = wcol + n*16 + lo;
        const float bb = b_er[col];
#pragma unroll
        for (int r = 0; r < 4; ++r) {
          const int rl = m*16 + hi*4 + r;
          const int byte = rl*512 + ((col*2) ^ ((rl & 7) << 4));
          *reinterpret_cast<f16*>(sm + byte) = (f16)(acc[m][n][r] + bb);
        }
      }
  }
  __syncthreads();

  // ---------------- pass S: accS = T @ Wl1^T ----------------
  {
    f32x4 accS[4][4] = {};
    for (int t = 0; t < 4; ++t) {
#pragma unroll
      for (int ks = 0; ks < 2; ++ks) {
        const int kc = t*8 + ks*4 + hi;
        const int b0 = t*128 + ks*64 + hi*16;
        f16x8 af[4], bf[4];
#pragma unroll
        for (int m = 0; m < 4; ++m) {
          const int r = m*16 + lo;
          af[m] = *reinterpret_cast<const f16x8*>(sm + r*512 + (b0 ^ ((r & 7) << 4)));
        }
#pragma unroll
        for (int n = 0; n < 4; ++n)
          bf[n] = *reinterpret_cast<const f16x8*>(Bl1 + ((size_t)kc*256 + (wcol + n*16 + lo)) * 8);
#pragma unroll
        for (int m = 0; m < 4; ++m)
#pragma unroll
          for (int n = 0; n < 4; ++n)
            accS[m][n] = __builtin_amdgcn_mfma_f32_16x16x32_f16(af[m], bf[n], accS[m][n], 0, 0, 0);
      }
    }
#pragma unroll
    for (int m = 0; m < 4; ++m) {
#pragma unroll
      for (int r = 0; r < 4; ++r) {
        float p = 0.f;
#pragma unroll
        for (int n = 0; n < 4; ++n) {
          const int col = wcol + n*16 + lo;
          p += Wl2[col] * fmaxf(accS[m][n][r] + bl1[col], 0.0f);
        }
        p += __shfl_xor(p, 1); p += __shfl_xor(p, 2);
        p += __shfl_xor(p, 4); p += __shfl_xor(p, 8);
        if (lo == 0) red[m*16 + hi*4 + r][wave] = p;
      }
    }
  }

  // ---------------- pass M: accM = T @ Wev^T ----------------
  {
    f32x4 accM[4][4] = {};
    for (int t = 0; t < 4; ++t) {
#pragma unroll
      for (int ks = 0; ks < 2; ++ks) {
        const int kc = t*8 + ks*4 + hi;
        const int b0 = t*128 + ks*64 + hi*16;
        f16x8 af[4], bf[4];
#pragma unroll
        for (int m = 0; m < 4; ++m) {
          const int r = m*16 + lo;
          af[m] = *reinterpret_cast<const f16x8*>(sm + r*512 + (b0 ^ ((r & 7) << 4)));
        }
#pragma unroll
        for (int n = 0; n < 4; ++n)
          bf[n] = *reinterpret_cast<const f16x8*>(Bev + ((size_t)kc*256 + (wcol + n*16 + lo)) * 8);
#pragma unroll
        for (int m = 0; m < 4; ++m)
#pragma unroll
          for (int n = 0; n < 4; ++n)
            accM[m][n] = __builtin_amdgcn_mfma_f32_16x16x32_f16(af[m], bf[n], accM[m][n], 0, 0, 0);
      }
    }
    __syncthreads();   // all T reads done; overwrite with Mpre (linear)
    const int rxb = (blockIdx.x >> 6) * 64;
#pragma unroll
    for (int m = 0; m < 4; ++m)
#pragma unroll
      for (int n = 0; n < 4; ++n) {
        const int col = wcol + n*16 + lo;
        const float bb = bm[col];
#pragma unroll
        for (int r = 0; r < 4; ++r) {
          const int rl = m*16 + hi*4 + r;
          float v = accM[m][n][r] + XpH[(size_t)(rxb + rl)*256 + col] + bb;
          *reinterpret_cast<f16*>(sm + rl*512 + col*2) = (f16)fmaxf(v, 0.0f);
        }
      }
  }
  __syncthreads();
#pragma unroll
  for (int i = 0; i < 8; ++i) {
    const int lin = i*4096 + tid*16;
    f16x8 v = *reinterpret_cast<const f16x8*>(sm + lin);
    *reinterpret_cast<f16x8*>((char*)Mpreh + arow0*512 + lin) = v;
  }
  if (tid < 64)
    S1[arow0 + tid] = sigmoidf_(bl2[0] + red[tid][0] + red[tid][1] + red[tid][2] + red[tid][3]);
}

// ---------------------------------------------------------------------------
// Score pass 2 (transposed gather, reg-staged) + fused msum.
// ---------------------------------------------------------------------------
__global__ __launch_bounds__(256) void attn2_ms(
    const f16* __restrict__ Mpreh, const float* __restrict__ S1,
    const f16* __restrict__ Bl1, const float* __restrict__ bl1,
    const float* __restrict__ Wl2, const float* __restrict__ bl2,
    float* __restrict__ adj, f16* __restrict__ xf)
{
  const int blk = blockIdx.x;
  const int b = blk >> 6, v = blk & 63;
  const int tid = threadIdx.x;
  const int wave = tid >> 6, l = tid & 63;
  const int lo = l & 15, hi = l >> 4;
  const int wcol = wave * 64;
  __shared__ f16 As[2][64][72];
  __shared__ float red[64][4];
  __shared__ float s1s[64];
  __shared__ float s2s[64];
  f32x4 acc[4][4] = {};
  const int rr0 = tid >> 3, part = tid & 7;
  const size_t pbase = (size_t)b * 4096 + v;
  f16x8 ga, gb;

  if (tid < 64) s1s[tid] = S1[pbase + (size_t)tid * 64];
  __syncthreads();

#define A2_LOAD(T)                                                              \
  { ga = *reinterpret_cast<const f16x8*>(Mpreh + (pbase + (size_t)rr0*64)*256 + (T)*64 + part*8);     \
    gb = *reinterpret_cast<const f16x8*>(Mpreh + (pbase + (size_t)(rr0+32)*64)*256 + (T)*64 + part*8); }
#define A2_WRITE(BUF)                                                           \
  { f16 sa = (f16)s1s[rr0], sb = (f16)s1s[rr0 + 32];                            \
    f16x8 ha = ga, hb = gb;                                                     \
    _Pragma("unroll") for (int j = 0; j < 8; ++j) { ha[j] *= sa; hb[j] *= sb; } \
    *reinterpret_cast<f16x8*>(&As[BUF][rr0][part*8]) = ha;                      \
    *reinterpret_cast<f16x8*>(&As[BUF][rr0 + 32][part*8]) = hb; }

  A2_LOAD(0); A2_WRITE(0);
  for (int t = 0; t < 4; ++t) {
    __syncthreads();
    if (t < 3) A2_LOAD(t + 1);
    const int cur = t & 1;
#pragma unroll
    for (int ks = 0; ks < 2; ++ks) {
      f16x8 af[4], bf[4];
      const int kc = t*8 + ks*4 + hi;
#pragma unroll
      for (int m = 0; m < 4; ++m)
        af[m] = *reinterpret_cast<const f16x8*>(&As[cur][m*16 + lo][ks*32 + hi*8]);
#pragma unroll
      for (int n = 0; n < 4; ++n)
        bf[n] = *reinterpret_cast<const f16x8*>(Bl1 + ((size_t)kc*256 + (wcol + n*16 + lo)) * 8);
#pragma unroll
      for (int m = 0; m < 4; ++m)
#pragma unroll
        for (int n = 0; n < 4; ++n)
          acc[m][n] = __builtin_amdgcn_mfma_f32_16x16x32_f16(af[m], bf[n], acc[m][n], 0, 0, 0);
    }
    if (t < 3) A2_WRITE(cur ^ 1);
  }
#undef A2_LOAD
#undef A2_WRITE
#pragma unroll
  for (int m = 0; m < 4; ++m) {
#pragma unroll
    for (int r = 0; r < 4; ++r) {
      float p = 0.f;
#pragma unroll
      for (int n = 0; n < 4; ++n) {
        const int col = wcol + n*16 + lo;
        p += Wl2[col] * fmaxf(acc[m][n][r] + bl1[col], 0.0f);
      }
      p += __shfl_xor(p, 1); p += __shfl_xor(p, 2);
      p += __shfl_xor(p, 4); p += __shfl_xor(p, 8);
      if (lo == 0) red[m*16 + hi*4 + r][wave] = p;
    }
  }
  __syncthreads();
  if (tid < 64) {
    float s = bl2[0] + red[tid][0] + red[tid][1] + red[tid][2] + red[tid][3];
    adj[(size_t)b*4096 + (size_t)v*64 + tid] = s;
    s2s[tid] = sigmoidf_(s);
  }
  __syncthreads();
  const int c = tid;
  const f16* mp = Mpreh + (size_t)blk * 64 * 256 + c;
  float accx = 0.f;
#pragma unroll 8
  for (int w = 0; w < 64; ++w)
    accx += (float)mp[(size_t)w * 256] * s2s[w];
  xf[(size_t)blk * 256 + c] = (f16)accx;
}

// ---------------------------------------------------------------------------
// Fused Xp + XpH, BM=16, grid 64
// ---------------------------------------------------------------------------
__global__ __launch_bounds__(256) void xp_xph16(
    const float* __restrict__ A, const f16* __restrict__ Bnr,
    const float* __restrict__ b_nr, const f16* __restrict__ Bhw,
    float* __restrict__ Xp, f16* __restrict__ Xpf, float* __restrict__ XpH)
{
  const int tid = threadIdx.x;
  const int wave = tid >> 6, l = tid & 63;
  const int lo = l & 15, hi = l >> 4;
  const int wcol = wave * 64;
  __shared__ f16 As[2][16][72];
  __shared__ f16 XpS[16][264];
  f32x4 acc[4] = {};
  const size_t arow0 = (size_t)blockIdx.x * 16;
  const int srow = tid >> 4, spart = tid & 15;
  const float* abase = A + (arow0 + srow) * FN;
  float4 g;
  const float4 z4 = make_float4(0.f, 0.f, 0.f, 0.f);

#define XQ_LOAD(T)                                                          \
  { int kb = (T)*64 + spart*4;                                              \
    g = (kb + 4 <= FN) ? *(const float4*)(abase + kb) : z4; }
#define XQ_WRITE(BUF)                                                       \
  { *reinterpret_cast<f16x4*>(&As[BUF][srow][spart*4]) = cvtp4(g); }

  XQ_LOAD(0); XQ_WRITE(0);
  for (int t = 0; t < 18; ++t) {
    __syncthreads();
    if (t < 17) XQ_LOAD(t + 1);
    const int cur = t & 1;
#pragma unroll
    for (int ks = 0; ks < 2; ++ks) {
      const int kc = t*8 + ks*4 + hi;
      f16x8 af = *reinterpret_cast<const f16x8*>(&As[cur][lo][ks*32 + hi*8]);
      f16x8 bf[4];
#pragma unroll
      for (int n = 0; n < 4; ++n)
        bf[n] = *reinterpret_cast<const f16x8*>(Bnr + ((size_t)kc*256 + (wcol + n*16 + lo)) * 8);
#pragma unroll
      for (int n = 0; n < 4; ++n)
        acc[n] = __builtin_amdgcn_mfma_f32_16x16x32_f16(af, bf[n], acc[n], 0, 0, 0);
    }
    if (t < 17) XQ_WRITE(cur ^ 1);
  }
#undef XQ_LOAD
#undef XQ_WRITE
#pragma unroll
  for (int n = 0; n < 4; ++n) {
    const int col = wcol + n*16 + lo;
    const float bb = b_nr[col];
#pragma unroll
    for (int r = 0; r < 4; ++r) {
      const size_t row = arow0 + hi*4 + r;
      float v = acc[n][r] + bb;
      Xp[row * 256 + col] = v;
      f16 hv = (f16)v;
      Xpf[row * 256 + col] = hv;
      XpS[hi*4 + r][col] = hv;
    }
  }
  __syncthreads();
  f32x4 acch[4] = {};
  for (int t = 0; t < 4; ++t) {
#pragma unroll
    for (int ks = 0; ks < 2; ++ks) {
      const int kc = t*8 + ks*4 + hi;
      f16x8 af = *reinterpret_cast<const f16x8*>(&XpS[lo][t*64 + ks*32 + hi*8]);
      f16x8 bf[4];
#pragma unroll
      for (int n = 0; n < 4; ++n)
        bf[n] = *reinterpret_cast<const f16x8*>(Bhw + ((size_t)kc*256 + (wcol + n*16 + lo)) * 8);
#pragma unroll
      for (int n = 0; n < 4; ++n)
        acch[n] = __builtin_amdgcn_mfma_f32_16x16x32_f16(af, bf[n], acch[n], 0, 0, 0);
    }
  }
#pragma unroll
  for (int n = 0; n < 4; ++n) {
    const int col = wcol + n*16 + lo;
#pragma unroll
    for (int r = 0; r < 4; ++r)
      XpH[(arow0 + hi*4 + r) * 256 + col] = acch[n][r];
  }
}

// ---------------------------------------------------------------------------
// Merged gi/gh GEMM, BM=16: grid (64, 6)
// ---------------------------------------------------------------------------
__global__ __launch_bounds__(256) void gigh16(
    const f16* __restrict__ xf, const f16* __restrict__ Xpf,
    const f16* __restrict__ Wi8, const f16* __restrict__ Wh8,
    const float* __restrict__ bi, const float* __restrict__ bh,
    float* __restrict__ gi, float* __restrict__ gh)
{
  const int rb = blockIdx.x;
  int cb = blockIdx.y;
  const f16* A; const f16* Bp; const float* bias; float* C;
  if (cb < 3) { A = xf;  Bp = Wi8; bias = bi; C = gi; }
  else        { A = Xpf; Bp = Wh8; bias = bh; C = gh; cb -= 3; }
  const int tid = threadIdx.x;
  const int wave = tid >> 6, l = tid & 63;
  const int lo = l & 15, hi = l >> 4;
  const int wcol = cb * 256 + wave * 64;
  __shared__ f16 As[16][264];
  f32x4 acc[4] = {};
  const size_t arow0 = (size_t)rb * 16;

#pragma unroll
  for (int i = 0; i < 2; ++i) {
    int idx = i * 256 + tid;
    int rr = idx >> 5, part = idx & 31;
    *reinterpret_cast<f16x8*>(&As[rr][part*8]) =
        *reinterpret_cast<const f16x8*>(A + (arow0 + rr)*256 + part*8);
  }
  __syncthreads();

  for (int t = 0; t < 4; ++t) {
#pragma unroll
    for (int ks = 0; ks < 2; ++ks) {
      const int kc = t*8 + ks*4 + hi;
      f16x8 af = *reinterpret_cast<const f16x8*>(&As[lo][t*64 + ks*32 + hi*8]);
      f16x8 bf[4];
#pragma unroll
      for (int n = 0; n < 4; ++n)
        bf[n] = *reinterpret_cast<const f16x8*>(Bp + ((size_t)kc*768 + (wcol + n*16 + lo)) * 8);
#pragma unroll
      for (int n = 0; n < 4; ++n)
        acc[n] = __builtin_amdgcn_mfma_f32_16x16x32_f16(af, bf[n], acc[n], 0, 0, 0);
    }
  }
#pragma unroll
  for (int n = 0; n < 4; ++n) {
    const int col = wcol + n*16 + lo;
    const float bb = bias[col];
#pragma unroll
    for (int r = 0; r < 4; ++r)
      C[(arow0 + hi*4 + r) * 768 + col] = acc[n][r] + bb;
  }
}

// ---------------------------------------------------------------------------
// Labels GEMM with GRU fused into staging, BM=16: grid (64, 3)
// ---------------------------------------------------------------------------
__global__ __launch_bounds__(256) void labels_gru16(
    const float* __restrict__ gi, const float* __restrict__ gh,
    const float* __restrict__ Xp, const f16* __restrict__ Wro8,
    const float* __restrict__ bro, float* __restrict__ labels)
{
  const int rb = blockIdx.x, cb = blockIdx.y;
  const int tid = threadIdx.x;
  const int wave = tid >> 6, l = tid & 63;
  const int lo = l & 15, hi = l >> 4;
  const int wcol = cb * 256 + wave * 64;
  __shared__ f16 As[16][264];
  f32x4 acc[4] = {};
  const size_t arow0 = (size_t)rb * 16;

  {
    const int rr = tid >> 4, c0 = (tid & 15) * 16;
    const float* gir = gi + (arow0 + rr) * 768;
    const float* ghr = gh + (arow0 + rr) * 768;
    const float* xpr = Xp + (arow0 + rr) * 256;
#pragma unroll
    for (int j = 0; j < 16; ++j) {
      const int c = c0 + j;
      float r = sigmoidf_(gir[c] + ghr[c]);
      float z = sigmoidf_(gir[256 + c] + ghr[256 + c]);
      float n = tanhf(gir[512 + c] + r * ghr[512 + c]);
      float h = xpr[c];
      As[rr][c] = (f16)((1.0f - z) * n + z * h);
    }
  }
  __syncthreads();

  for (int t = 0; t < 4; ++t) {
#pragma unroll
    for (int ks = 0; ks < 2; ++ks) {
      const int kc = t*8 + ks*4 + hi;
      f16x8 af = *reinterpret_cast<const f16x8*>(&As[lo][t*64 + ks*32 + hi*8]);
      f16x8 bf[4];
#pragma unroll
      for (int n = 0; n < 4; ++n)
        bf[n] = *reinterpret_cast<const f16x8*>(Wro8 + ((size_t)kc*768 + (wcol + n*16 + lo)) * 8);
#pragma unroll
      for (int n = 0; n < 4; ++n)
        acc[n] = __builtin_amdgcn_mfma_f32_16x16x32_f16(af, bf[n], acc[n], 0, 0, 0);
    }
  }
#pragma unroll
  for (int n = 0; n < 4; ++n) {
    const int col = wcol + n*16 + lo;
    if (col < KC) {
      const float bb = bro[col];
#pragma unroll
      for (int r = 0; r < 4; ++r)
        labels[(arow0 + hi*4 + r) * (size_t)KC + col] = acc[n][r] + bb;
    }
  }
}

} // namespace

extern "C" void kernel_launch(void* const* d_in, const int* in_sizes, int n_in,
                              void* d_out, int out_size, void* d_ws, size_t ws_size,
                              hipStream_t stream)
{
  const float* ef   = (const float*)d_in[0];
  const float* nf   = (const float*)d_in[1];
  const float* W_er = (const float*)d_in[7];
  const float* b_er = (const float*)d_in[8];
  const float* W_nr = (const float*)d_in[9];
  const float* b_nr = (const float*)d_in[10];
  const float* Wl1  = (const float*)d_in[11];
  const float* bl1  = (const float*)d_in[12];
  const float* Wl2  = (const float*)d_in[13];
  const float* bl2  = (const float*)d_in[14];
  const float* Wm   = (const float*)d_in[15];
  const float* bm   = (const float*)d_in[16];
  const float* Wi   = (const float*)d_in[17];
  const float* bi   = (const float*)d_in[18];
  const float* Wh   = (const float*)d_in[19];
  const float* bh   = (const float*)d_in[20];
  const float* Wro  = (const float*)d_in[21];
  const float* bro  = (const float*)d_in[22];

  float* ws = (float*)d_ws;
  float* Xp    = ws + OFF_XP;
  f16*   Xpf   = (f16*)(ws + OFF_XPF);
  float* XpH   = ws + OFF_XPH;
  float* S1    = ws + OFF_S1;
  f16*   xf    = (f16*)(ws + OFF_XF);
  float* gi    = ws + OFF_GI;
  float* gh    = ws + OFF_GH;
  f16*   Wer8  = (f16*)(ws + OFF_WER8);
  f16*   Wnr8  = (f16*)(ws + OFF_WNR8);
  f16*   Wev8  = (f16*)(ws + OFF_WEV8);
  f16*   Whw8  = (f16*)(ws + OFF_WHW8);
  f16*   Wl18  = (f16*)(ws + OFF_WL18);
  f16*   Wi8   = (f16*)(ws + OFF_WI8);
  f16*   Wh8   = (f16*)(ws + OFF_WH8);
  f16*   Wro8  = (f16*)(ws + OFF_WRO8);
  f16*   Mpreh = (f16*)(ws + OFF_MPREH);
  float* adj    = (float*)d_out;
  float* labels = (float*)d_out + PAIRS;

  dim3 blk(256);

  cast_all<<<dim3(680), blk, 0, stream>>>(W_er, W_nr, Wm, Wl1, Wi, Wh, Wro,
                                          Wer8, Wnr8, Wev8, Whw8, Wl18, Wi8, Wh8, Wro8);
  xp_xph16<<<dim3(64), blk, 0, stream>>>(nf, Wnr8, b_nr, Whw8, Xp, Xpf, XpH);
  e0_sm<<<dim3(PAIRS / 64), blk, 0, stream>>>(ef, Wer8, b_er, Wl18, Wev8,
                                              bl1, Wl2, bl2, XpH, bm,
                                              S1, Mpreh);
  attn2_ms<<<dim3(PAIRS / 64), blk, 0, stream>>>(Mpreh, S1, Wl18, bl1, Wl2, bl2,
                                                 adj, xf);
  gigh16<<<dim3(64, 6), blk, 0, stream>>>(xf, Xpf, Wi8, Wh8, bi, bh, gi, gh);
  labels_gru16<<<dim3(64, 3), blk, 0, stream>>>(gi, gh, Xp, Wro8, bro, labels);
}

// Round 13
// 223.036 us; speedup vs baseline: 1.4205x; 1.0125x over previous
//
#include <hip/hip_runtime.h>
#include <cmath>

namespace {

using f16 = _Float16;
typedef f16 f16x8 __attribute__((ext_vector_type(8)));
typedef f16 f16x4 __attribute__((ext_vector_type(4)));
typedef __fp16 h16x2 __attribute__((ext_vector_type(2)));
typedef float f32x4 __attribute__((ext_vector_type(4)));

constexpr int FE = 1216, FN = 1108, MD = 256, KC = 600;
constexpr int PAIRS = 65536, ROWS = 1024;

// workspace offsets (float units, all 16B-aligned)
constexpr size_t OFF_XP    = 0;                       // fp32 [1024][256]
constexpr size_t OFF_XPF   = OFF_XP    + 262144;      // f16  [1024][256]
constexpr size_t OFF_XPH   = OFF_XPF   + 131072;      // fp32 [1024][256]
constexpr size_t OFF_S1    = OFF_XPH   + 262144;      // fp32 [65536]
constexpr size_t OFF_S2    = OFF_S1    + 65536;       // (unused)
constexpr size_t OFF_XF    = OFF_S2    + 65536;       // f16  [1024][256]
constexpr size_t OFF_GI    = OFF_XF    + 131072;      // fp32 [1024][768]
constexpr size_t OFF_GH    = OFF_GI    + 786432;      // fp32 [1024][768]
constexpr size_t OFF_HNF   = OFF_GH    + 786432;      // (unused)
constexpr size_t OFF_WER8  = OFF_HNF   + 131072;      // f16 prefrag 152*256*8
constexpr size_t OFF_WNR8  = OFF_WER8  + 155648;      // 144*256*8
constexpr size_t OFF_WEV8  = OFF_WNR8  + 147456;      // 32*256*8
constexpr size_t OFF_WHW8  = OFF_WEV8  + 32768;       // 32*256*8
constexpr size_t OFF_WL18  = OFF_WHW8  + 32768;       // 32*256*8
constexpr size_t OFF_WI8   = OFF_WL18  + 32768;       // 32*768*8
constexpr size_t OFF_WH8   = OFF_WI8   + 98304;       // 32*768*8
constexpr size_t OFF_WRO8  = OFF_WH8   + 98304;       // 32*768*8 (KC pad 768)
constexpr size_t OFF_E0H   = OFF_WRO8  + 98304;       // (unused)
constexpr size_t OFF_MPREH = OFF_E0H   + 8388608;     // f16 [65536][256]

__device__ __forceinline__ float sigmoidf_(float x) { return 1.0f / (1.0f + expf(-x)); }

__device__ __forceinline__ void dma16(const void* g, void* l) {
  __builtin_amdgcn_global_load_lds((const unsigned int*)g, (unsigned int*)l, 16, 0, 0);
}

__device__ __forceinline__ f16x8 cvtp(f32x4 a, f32x4 b) {
  union { h16x2 q[4]; f16x8 h; } u;
  u.q[0] = __builtin_amdgcn_cvt_pkrtz(a[0], a[1]);
  u.q[1] = __builtin_amdgcn_cvt_pkrtz(a[2], a[3]);
  u.q[2] = __builtin_amdgcn_cvt_pkrtz(b[0], b[1]);
  u.q[3] = __builtin_amdgcn_cvt_pkrtz(b[2], b[3]);
  return u.h;
}

__device__ __forceinline__ f16x4 cvtp4(const float4& g) {
  union { h16x2 q[2]; f16x4 h; } u;
  u.q[0] = __builtin_amdgcn_cvt_pkrtz(g.x, g.y);
  u.q[1] = __builtin_amdgcn_cvt_pkrtz(g.z, g.w);
  return u.h;
}

// ---------------------------------------------------------------------------
// cast_all: prefragment all weight matrices into f16 MFMA-B layout
// ---------------------------------------------------------------------------
__global__ __launch_bounds__(256) void cast_all(
    const float* __restrict__ W_er, const float* __restrict__ W_nr,
    const float* __restrict__ Wm,   const float* __restrict__ Wl1,
    const float* __restrict__ Wi,   const float* __restrict__ Wh,
    const float* __restrict__ Wro,
    f16* __restrict__ Wer8, f16* __restrict__ Wnr8, f16* __restrict__ Wev8,
    f16* __restrict__ Whw8, f16* __restrict__ Wl18, f16* __restrict__ Wi8,
    f16* __restrict__ Wh8,  f16* __restrict__ Wro8)
{
  int b = blockIdx.x, t = threadIdx.x;
  const float* W; f16* out; int ldw, koff, K, N, Npad, kc, nb;
  if (b < 152)      { W=W_er; out=Wer8; ldw=FE;  koff=0;   K=FE;  N=256; Npad=256; kc=b;     nb=0; }
  else if (b < 296) { b-=152; W=W_nr; out=Wnr8; ldw=FN;  koff=0;   K=FN;  N=256; Npad=256; kc=b; nb=0; }
  else if (b < 328) { b-=296; W=Wm;   out=Wev8; ldw=512; koff=256; K=256; N=256; Npad=256; kc=b; nb=0; }
  else if (b < 360) { b-=328; W=Wm;   out=Whw8; ldw=512; koff=0;   K=256; N=256; Npad=256; kc=b; nb=0; }
  else if (b < 392) { b-=360; W=Wl1;  out=Wl18; ldw=256; koff=0;   K=256; N=256; Npad=256; kc=b; nb=0; }
  else if (b < 488) { b-=392; W=Wi;   out=Wi8;  ldw=256; koff=0;   K=256; N=768; Npad=768; kc=b&31; nb=(b>>5)*256; }
  else if (b < 584) { b-=488; W=Wh;   out=Wh8;  ldw=256; koff=0;   K=256; N=768; Npad=768; kc=b&31; nb=(b>>5)*256; }
  else              { b-=584; W=Wro;  out=Wro8; ldw=256; koff=0;   K=256; N=600; Npad=768; kc=b&31; nb=(b>>5)*256; }
  int n = nb + t;
  if (n >= Npad) return;
  f16x8 h;
#pragma unroll
  for (int j = 0; j < 8; ++j) {
    int k = kc * 8 + j;
    float v = (k < K && n < N) ? W[(size_t)n * ldw + koff + k] : 0.0f;
    h[j] = (f16)v;
  }
  *reinterpret_cast<f16x8*>(out + ((size_t)kc * Npad + n) * 8) = h;
}

// ---------------------------------------------------------------------------
// Fused E0 + score-1 + Mpre.  Occupancy-first design (4 blocks/CU target):
//  - BK=32, A-only DMA staging, 3 x 8KB buffers (T tile overlays, 33KB LDS)
//  - B via preloaded vector loads (4 frags/chunk, L2-resident)
//  - __launch_bounds__(256,4) caps VGPR at 128 -> 16 waves/CU
// Then E0 tile -> LDS T (swizzled); S pass; M pass; Mpre out.
// ---------------------------------------------------------------------------
__global__ __launch_bounds__(256, 4) void e0_sm(
    const float* __restrict__ A, const f16* __restrict__ Ber,
    const float* __restrict__ b_er,
    const f16* __restrict__ Bl1, const f16* __restrict__ Bev,
    const float* __restrict__ bl1, const float* __restrict__ Wl2,
    const float* __restrict__ bl2,
    const float* __restrict__ XpH, const float* __restrict__ bm,
    float* __restrict__ S1, f16* __restrict__ Mpreh)
{
  const int tid = threadIdx.x;
  const int wave = tid >> 6, l = tid & 63;
  const int lo = l & 15, hi = l >> 4;
  const int wcol = wave * 64;
  alignas(16) __shared__ char sm[32768];   // 3x8KB stage (24KB) overlaid by 32KB T
  __shared__ float red[64][4];
  const size_t arow0 = (size_t)blockIdx.x * 64;

  // ---------------- phase E0 ----------------
  {
    f32x4 acc[4][4] = {};
    // A DMA sources (2/wave): row-major [64][128B], slot-XOR swizzled source
    const char* asrc[2]; int adst[2];
#pragma unroll
    for (int j = 0; j < 2; ++j) {
      const int row = wave*16 + j*8 + (l >> 3);
      const int slot = (l & 7) ^ (row & 7);
      asrc[j] = (const char*)(A + (arow0 + row) * FE + slot * 4);
      adst[j] = wave*2048 + j*1024 + l*16;
    }

#define CH_ISSUE(P)                                                           \
    { char* bb = sm + (P)*8192;                                               \
      dma16(asrc[0], bb + adst[0]); asrc[0] += 128;                           \
      dma16(asrc[1], bb + adst[1]); asrc[1] += 128; }

    CH_ISSUE(0)
    CH_ISSUE(1)

    for (int t = 0; t < 38; ++t) {
      if (t < 37) { asm volatile("s_waitcnt vmcnt(2)" ::: "memory"); }
      else        { asm volatile("s_waitcnt vmcnt(0)" ::: "memory"); }
      __builtin_amdgcn_sched_barrier(0);
      __builtin_amdgcn_s_barrier();
      __builtin_amdgcn_sched_barrier(0);

      // B preload BEFORE the next DMA issue (newest DMAs survive B-waits)
      f16x8 bf[4];
#pragma unroll
      for (int n = 0; n < 4; ++n) {
        const int kc = t*4 + hi;
        bf[n] = *reinterpret_cast<const f16x8*>(Ber + ((size_t)kc*256 + (wcol + n*16 + lo)) * 8);
      }
      __builtin_amdgcn_sched_barrier(0);
      if (t < 36) { CH_ISSUE((t + 2) % 3) }
      __builtin_amdgcn_sched_barrier(0);

      const char* Ab = sm + (t % 3) * 8192;
      f16x8 af[4];
#pragma unroll
      for (int m = 0; m < 4; ++m) {
        const int r = m*16 + lo;
        const int s0 = (2*hi)     ^ (r & 7);
        const int s1 = (2*hi + 1) ^ (r & 7);
        f32x4 a0 = *reinterpret_cast<const f32x4*>(Ab + r*128 + s0*16);
        f32x4 a1 = *reinterpret_cast<const f32x4*>(Ab + r*128 + s1*16);
        af[m] = cvtp(a0, a1);
      }
#pragma unroll
      for (int m = 0; m < 4; ++m)
#pragma unroll
        for (int n = 0; n < 4; ++n)
          acc[m][n] = __builtin_amdgcn_mfma_f32_16x16x32_f16(af[m], bf[n], acc[m][n], 0, 0, 0);
    }
#undef CH_ISSUE

    __syncthreads();     // stage buffers dead -> reuse as T
    // E0 tile -> T (f16, swizzled 512B rows)
#pragma unroll
    for (int m = 0; m < 4; ++m)
#pragma unroll
      for (int n = 0; n < 4; ++n) {
        const int col = wcol + n*16 + lo;
        const float bb = b_er[col];
#pragma unroll
        for (int r = 0; r < 4; ++r) {
          const int rl = m*16 + hi*4 + r;
          const int byte = rl*512 + ((col*2) ^ ((rl & 7) << 4));
          *reinterpret_cast<f16*>(sm + byte) = (f16)(acc[m][n][r] + bb);
        }
      }
  }
  __syncthreads();

  // ---------------- pass S: accS = T @ Wl1^T ----------------
  {
    f32x4 accS[4][4] = {};
    for (int t = 0; t < 4; ++t) {
#pragma unroll
      for (int ks = 0; ks < 2; ++ks) {
        const int kc = t*8 + ks*4 + hi;
        const int b0 = t*128 + ks*64 + hi*16;
        f16x8 af[4], bf[4];
#pragma unroll
        for (int m = 0; m < 4; ++m) {
          const int r = m*16 + lo;
          af[m] = *reinterpret_cast<const f16x8*>(sm + r*512 + (b0 ^ ((r & 7) << 4)));
        }
#pragma unroll
        for (int n = 0; n < 4; ++n)
          bf[n] = *reinterpret_cast<const f16x8*>(Bl1 + ((size_t)kc*256 + (wcol + n*16 + lo)) * 8);
#pragma unroll
        for (int m = 0; m < 4; ++m)
#pragma unroll
          for (int n = 0; n < 4; ++n)
            accS[m][n] = __builtin_amdgcn_mfma_f32_16x16x32_f16(af[m], bf[n], accS[m][n], 0, 0, 0);
      }
    }
#pragma unroll
    for (int m = 0; m < 4; ++m) {
#pragma unroll
      for (int r = 0; r < 4; ++r) {
        float p = 0.f;
#pragma unroll
        for (int n = 0; n < 4; ++n) {
          const int col = wcol + n*16 + lo;
          p += Wl2[col] * fmaxf(accS[m][n][r] + bl1[col], 0.0f);
        }
        p += __shfl_xor(p, 1); p += __shfl_xor(p, 2);
        p += __shfl_xor(p, 4); p += __shfl_xor(p, 8);
        if (lo == 0) red[m*16 + hi*4 + r][wave] = p;
      }
    }
  }

  // ---------------- pass M: accM = T @ Wev^T ----------------
  {
    f32x4 accM[4][4] = {};
    for (int t = 0; t < 4; ++t) {
#pragma unroll
      for (int ks = 0; ks < 2; ++ks) {
        const int kc = t*8 + ks*4 + hi;
        const int b0 = t*128 + ks*64 + hi*16;
        f16x8 af[4], bf[4];
#pragma unroll
        for (int m = 0; m < 4; ++m) {
          const int r = m*16 + lo;
          af[m] = *reinterpret_cast<const f16x8*>(sm + r*512 + (b0 ^ ((r & 7) << 4)));
        }
#pragma unroll
        for (int n = 0; n < 4; ++n)
          bf[n] = *reinterpret_cast<const f16x8*>(Bev + ((size_t)kc*256 + (wcol + n*16 + lo)) * 8);
#pragma unroll
        for (int m = 0; m < 4; ++m)
#pragma unroll
          for (int n = 0; n < 4; ++n)
            accM[m][n] = __builtin_amdgcn_mfma_f32_16x16x32_f16(af[m], bf[n], accM[m][n], 0, 0, 0);
      }
    }
    __syncthreads();   // all T reads done; overwrite with Mpre (linear)
    const int rxb = (blockIdx.x >> 6) * 64;
#pragma unroll
    for (int m = 0; m < 4; ++m)
#pragma unroll
      for (int n = 0; n < 4; ++n) {
        const int col = wcol + n*16 + lo;
        const float bb = bm[col];
#pragma unroll
        for (int r = 0; r < 4; ++r) {
          const int rl = m*16 + hi*4 + r;
          float v = accM[m][n][r] + XpH[(size_t)(rxb + rl)*256 + col] + bb;
          *reinterpret_cast<f16*>(sm + rl*512 + col*2) = (f16)fmaxf(v, 0.0f);
        }
      }
  }
  __syncthreads();
#pragma unroll
  for (int i = 0; i < 8; ++i) {
    const int lin = i*4096 + tid*16;
    f16x8 v = *reinterpret_cast<const f16x8*>(sm + lin);
    *reinterpret_cast<f16x8*>((char*)Mpreh + arow0*512 + lin) = v;
  }
  if (tid < 64)
    S1[arow0 + tid] = sigmoidf_(bl2[0] + red[tid][0] + red[tid][1] + red[tid][2] + red[tid][3]);
}

// ---------------------------------------------------------------------------
// Score pass 2 (transposed gather, reg-staged) + fused msum.
// ---------------------------------------------------------------------------
__global__ __launch_bounds__(256) void attn2_ms(
    const f16* __restrict__ Mpreh, const float* __restrict__ S1,
    const f16* __restrict__ Bl1, const float* __restrict__ bl1,
    const float* __restrict__ Wl2, const float* __restrict__ bl2,
    float* __restrict__ adj, f16* __restrict__ xf)
{
  const int blk = blockIdx.x;
  const int b = blk >> 6, v = blk & 63;
  const int tid = threadIdx.x;
  const int wave = tid >> 6, l = tid & 63;
  const int lo = l & 15, hi = l >> 4;
  const int wcol = wave * 64;
  __shared__ f16 As[2][64][72];
  __shared__ float red[64][4];
  __shared__ float s1s[64];
  __shared__ float s2s[64];
  f32x4 acc[4][4] = {};
  const int rr0 = tid >> 3, part = tid & 7;
  const size_t pbase = (size_t)b * 4096 + v;
  f16x8 ga, gb;

  if (tid < 64) s1s[tid] = S1[pbase + (size_t)tid * 64];
  __syncthreads();

#define A2_LOAD(T)                                                              \
  { ga = *reinterpret_cast<const f16x8*>(Mpreh + (pbase + (size_t)rr0*64)*256 + (T)*64 + part*8);     \
    gb = *reinterpret_cast<const f16x8*>(Mpreh + (pbase + (size_t)(rr0+32)*64)*256 + (T)*64 + part*8); }
#define A2_WRITE(BUF)                                                           \
  { f16 sa = (f16)s1s[rr0], sb = (f16)s1s[rr0 + 32];                            \
    f16x8 ha = ga, hb = gb;                                                     \
    _Pragma("unroll") for (int j = 0; j < 8; ++j) { ha[j] *= sa; hb[j] *= sb; } \
    *reinterpret_cast<f16x8*>(&As[BUF][rr0][part*8]) = ha;                      \
    *reinterpret_cast<f16x8*>(&As[BUF][rr0 + 32][part*8]) = hb; }

  A2_LOAD(0); A2_WRITE(0);
  for (int t = 0; t < 4; ++t) {
    __syncthreads();
    if (t < 3) A2_LOAD(t + 1);
    const int cur = t & 1;
#pragma unroll
    for (int ks = 0; ks < 2; ++ks) {
      f16x8 af[4], bf[4];
      const int kc = t*8 + ks*4 + hi;
#pragma unroll
      for (int m = 0; m < 4; ++m)
        af[m] = *reinterpret_cast<const f16x8*>(&As[cur][m*16 + lo][ks*32 + hi*8]);
#pragma unroll
      for (int n = 0; n < 4; ++n)
        bf[n] = *reinterpret_cast<const f16x8*>(Bl1 + ((size_t)kc*256 + (wcol + n*16 + lo)) * 8);
#pragma unroll
      for (int m = 0; m < 4; ++m)
#pragma unroll
        for (int n = 0; n < 4; ++n)
          acc[m][n] = __builtin_amdgcn_mfma_f32_16x16x32_f16(af[m], bf[n], acc[m][n], 0, 0, 0);
    }
    if (t < 3) A2_WRITE(cur ^ 1);
  }
#undef A2_LOAD
#undef A2_WRITE
#pragma unroll
  for (int m = 0; m < 4; ++m) {
#pragma unroll
    for (int r = 0; r < 4; ++r) {
      float p = 0.f;
#pragma unroll
      for (int n = 0; n < 4; ++n) {
        const int col = wcol + n*16 + lo;
        p += Wl2[col] * fmaxf(acc[m][n][r] + bl1[col], 0.0f);
      }
      p += __shfl_xor(p, 1); p += __shfl_xor(p, 2);
      p += __shfl_xor(p, 4); p += __shfl_xor(p, 8);
      if (lo == 0) red[m*16 + hi*4 + r][wave] = p;
    }
  }
  __syncthreads();
  if (tid < 64) {
    float s = bl2[0] + red[tid][0] + red[tid][1] + red[tid][2] + red[tid][3];
    adj[(size_t)b*4096 + (size_t)v*64 + tid] = s;
    s2s[tid] = sigmoidf_(s);
  }
  __syncthreads();
  const int c = tid;
  const f16* mp = Mpreh + (size_t)blk * 64 * 256 + c;
  float accx = 0.f;
#pragma unroll 8
  for (int w = 0; w < 64; ++w)
    accx += (float)mp[(size_t)w * 256] * s2s[w];
  xf[(size_t)blk * 256 + c] = (f16)accx;
}

// ---------------------------------------------------------------------------
// Fused Xp + XpH, BM=16, grid 64
// ---------------------------------------------------------------------------
__global__ __launch_bounds__(256) void xp_xph16(
    const float* __restrict__ A, const f16* __restrict__ Bnr,
    const float* __restrict__ b_nr, const f16* __restrict__ Bhw,
    float* __restrict__ Xp, f16* __restrict__ Xpf, float* __restrict__ XpH)
{
  const int tid = threadIdx.x;
  const int wave = tid >> 6, l = tid & 63;
  const int lo = l & 15, hi = l >> 4;
  const int wcol = wave * 64;
  __shared__ f16 As[2][16][72];
  __shared__ f16 XpS[16][264];
  f32x4 acc[4] = {};
  const size_t arow0 = (size_t)blockIdx.x * 16;
  const int srow = tid >> 4, spart = tid & 15;
  const float* abase = A + (arow0 + srow) * FN;
  float4 g;
  const float4 z4 = make_float4(0.f, 0.f, 0.f, 0.f);

#define XQ_LOAD(T)                                                          \
  { int kb = (T)*64 + spart*4;                                              \
    g = (kb + 4 <= FN) ? *(const float4*)(abase + kb) : z4; }
#define XQ_WRITE(BUF)                                                       \
  { *reinterpret_cast<f16x4*>(&As[BUF][srow][spart*4]) = cvtp4(g); }

  XQ_LOAD(0); XQ_WRITE(0);
  for (int t = 0; t < 18; ++t) {
    __syncthreads();
    if (t < 17) XQ_LOAD(t + 1);
    const int cur = t & 1;
#pragma unroll
    for (int ks = 0; ks < 2; ++ks) {
      const int kc = t*8 + ks*4 + hi;
      f16x8 af = *reinterpret_cast<const f16x8*>(&As[cur][lo][ks*32 + hi*8]);
      f16x8 bf[4];
#pragma unroll
      for (int n = 0; n < 4; ++n)
        bf[n] = *reinterpret_cast<const f16x8*>(Bnr + ((size_t)kc*256 + (wcol + n*16 + lo)) * 8);
#pragma unroll
      for (int n = 0; n < 4; ++n)
        acc[n] = __builtin_amdgcn_mfma_f32_16x16x32_f16(af, bf[n], acc[n], 0, 0, 0);
    }
    if (t < 17) XQ_WRITE(cur ^ 1);
  }
#undef XQ_LOAD
#undef XQ_WRITE
#pragma unroll
  for (int n = 0; n < 4; ++n) {
    const int col = wcol + n*16 + lo;
    const float bb = b_nr[col];
#pragma unroll
    for (int r = 0; r < 4; ++r) {
      const size_t row = arow0 + hi*4 + r;
      float v = acc[n][r] + bb;
      Xp[row * 256 + col] = v;
      f16 hv = (f16)v;
      Xpf[row * 256 + col] = hv;
      XpS[hi*4 + r][col] = hv;
    }
  }
  __syncthreads();
  f32x4 acch[4] = {};
  for (int t = 0; t < 4; ++t) {
#pragma unroll
    for (int ks = 0; ks < 2; ++ks) {
      const int kc = t*8 + ks*4 + hi;
      f16x8 af = *reinterpret_cast<const f16x8*>(&XpS[lo][t*64 + ks*32 + hi*8]);
      f16x8 bf[4];
#pragma unroll
      for (int n = 0; n < 4; ++n)
        bf[n] = *reinterpret_cast<const f16x8*>(Bhw + ((size_t)kc*256 + (wcol + n*16 + lo)) * 8);
#pragma unroll
      for (int n = 0; n < 4; ++n)
        acch[n] = __builtin_amdgcn_mfma_f32_16x16x32_f16(af, bf[n], acch[n], 0, 0, 0);
    }
  }
#pragma unroll
  for (int n = 0; n < 4; ++n) {
    const int col = wcol + n*16 + lo;
#pragma unroll
    for (int r = 0; r < 4; ++r)
      XpH[(arow0 + hi*4 + r) * 256 + col] = acch[n][r];
  }
}

// ---------------------------------------------------------------------------
// Merged gi/gh GEMM, BM=16: grid (64, 6)
// ---------------------------------------------------------------------------
__global__ __launch_bounds__(256) void gigh16(
    const f16* __restrict__ xf, const f16* __restrict__ Xpf,
    const f16* __restrict__ Wi8, const f16* __restrict__ Wh8,
    const float* __restrict__ bi, const float* __restrict__ bh,
    float* __restrict__ gi, float* __restrict__ gh)
{
  const int rb = blockIdx.x;
  int cb = blockIdx.y;
  const f16* A; const f16* Bp; const float* bias; float* C;
  if (cb < 3) { A = xf;  Bp = Wi8; bias = bi; C = gi; }
  else        { A = Xpf; Bp = Wh8; bias = bh; C = gh; cb -= 3; }
  const int tid = threadIdx.x;
  const int wave = tid >> 6, l = tid & 63;
  const int lo = l & 15, hi = l >> 4;
  const int wcol = cb * 256 + wave * 64;
  __shared__ f16 As[16][264];
  f32x4 acc[4] = {};
  const size_t arow0 = (size_t)rb * 16;

#pragma unroll
  for (int i = 0; i < 2; ++i) {
    int idx = i * 256 + tid;
    int rr = idx >> 5, part = idx & 31;
    *reinterpret_cast<f16x8*>(&As[rr][part*8]) =
        *reinterpret_cast<const f16x8*>(A + (arow0 + rr)*256 + part*8);
  }
  __syncthreads();

  for (int t = 0; t < 4; ++t) {
#pragma unroll
    for (int ks = 0; ks < 2; ++ks) {
      const int kc = t*8 + ks*4 + hi;
      f16x8 af = *reinterpret_cast<const f16x8*>(&As[lo][t*64 + ks*32 + hi*8]);
      f16x8 bf[4];
#pragma unroll
      for (int n = 0; n < 4; ++n)
        bf[n] = *reinterpret_cast<const f16x8*>(Bp + ((size_t)kc*768 + (wcol + n*16 + lo)) * 8);
#pragma unroll
      for (int n = 0; n < 4; ++n)
        acc[n] = __builtin_amdgcn_mfma_f32_16x16x32_f16(af, bf[n], acc[n], 0, 0, 0);
    }
  }
#pragma unroll
  for (int n = 0; n < 4; ++n) {
    const int col = wcol + n*16 + lo;
    const float bb = bias[col];
#pragma unroll
    for (int r = 0; r < 4; ++r)
      C[(arow0 + hi*4 + r) * 768 + col] = acc[n][r] + bb;
  }
}

// ---------------------------------------------------------------------------
// Labels GEMM with GRU fused into staging, BM=16: grid (64, 3)
// ---------------------------------------------------------------------------
__global__ __launch_bounds__(256) void labels_gru16(
    const float* __restrict__ gi, const float* __restrict__ gh,
    const float* __restrict__ Xp, const f16* __restrict__ Wro8,
    const float* __restrict__ bro, float* __restrict__ labels)
{
  const int rb = blockIdx.x, cb = blockIdx.y;
  const int tid = threadIdx.x;
  const int wave = tid >> 6, l = tid & 63;
  const int lo = l & 15, hi = l >> 4;
  const int wcol = cb * 256 + wave * 64;
  __shared__ f16 As[16][264];
  f32x4 acc[4] = {};
  const size_t arow0 = (size_t)rb * 16;

  {
    const int rr = tid >> 4, c0 = (tid & 15) * 16;
    const float* gir = gi + (arow0 + rr) * 768;
    const float* ghr = gh + (arow0 + rr) * 768;
    const float* xpr = Xp + (arow0 + rr) * 256;
#pragma unroll
    for (int j = 0; j < 16; ++j) {
      const int c = c0 + j;
      float r = sigmoidf_(gir[c] + ghr[c]);
      float z = sigmoidf_(gir[256 + c] + ghr[256 + c]);
      float n = tanhf(gir[512 + c] + r * ghr[512 + c]);
      float h = xpr[c];
      As[rr][c] = (f16)((1.0f - z) * n + z * h);
    }
  }
  __syncthreads();

  for (int t = 0; t < 4; ++t) {
#pragma unroll
    for (int ks = 0; ks < 2; ++ks) {
      const int kc = t*8 + ks*4 + hi;
      f16x8 af = *reinterpret_cast<const f16x8*>(&As[lo][t*64 + ks*32 + hi*8]);
      f16x8 bf[4];
#pragma unroll
      for (int n = 0; n < 4; ++n)
        bf[n] = *reinterpret_cast<const f16x8*>(Wro8 + ((size_t)kc*768 + (wcol + n*16 + lo)) * 8);
#pragma unroll
      for (int n = 0; n < 4; ++n)
        acc[n] = __builtin_amdgcn_mfma_f32_16x16x32_f16(af, bf[n], acc[n], 0, 0, 0);
    }
  }
#pragma unroll
  for (int n = 0; n < 4; ++n) {
    const int col = wcol + n*16 + lo;
    if (col < KC) {
      const float bb = bro[col];
#pragma unroll
      for (int r = 0; r < 4; ++r)
        labels[(arow0 + hi*4 + r) * (size_t)KC + col] = acc[n][r] + bb;
    }
  }
}

} // namespace

extern "C" void kernel_launch(void* const* d_in, const int* in_sizes, int n_in,
                              void* d_out, int out_size, void* d_ws, size_t ws_size,
                              hipStream_t stream)
{
  const float* ef   = (const float*)d_in[0];
  const float* nf   = (const float*)d_in[1];
  const float* W_er = (const float*)d_in[7];
  const float* b_er = (const float*)d_in[8];
  const float* W_nr = (const float*)d_in[9];
  const float* b_nr = (const float*)d_in[10];
  const float* Wl1  = (const float*)d_in[11];
  const float* bl1  = (const float*)d_in[12];
  const float* Wl2  = (const float*)d_in[13];
  const float* bl2  = (const float*)d_in[14];
  const float* Wm   = (const float*)d_in[15];
  const float* bm   = (const float*)d_in[16];
  const float* Wi   = (const float*)d_in[17];
  const float* bi   = (const float*)d_in[18];
  const float* Wh   = (const float*)d_in[19];
  const float* bh   = (const float*)d_in[20];
  const float* Wro  = (const float*)d_in[21];
  const float* bro  = (const float*)d_in[22];

  float* ws = (float*)d_ws;
  float* Xp    = ws + OFF_XP;
  f16*   Xpf   = (f16*)(ws + OFF_XPF);
  float* XpH   = ws + OFF_XPH;
  float* S1    = ws + OFF_S1;
  f16*   xf    = (f16*)(ws + OFF_XF);
  float* gi    = ws + OFF_GI;
  float* gh    = ws + OFF_GH;
  f16*   Wer8  = (f16*)(ws + OFF_WER8);
  f16*   Wnr8  = (f16*)(ws + OFF_WNR8);
  f16*   Wev8  = (f16*)(ws + OFF_WEV8);
  f16*   Whw8  = (f16*)(ws + OFF_WHW8);
  f16*   Wl18  = (f16*)(ws + OFF_WL18);
  f16*   Wi8   = (f16*)(ws + OFF_WI8);
  f16*   Wh8   = (f16*)(ws + OFF_WH8);
  f16*   Wro8  = (f16*)(ws + OFF_WRO8);
  f16*   Mpreh = (f16*)(ws + OFF_MPREH);
  float* adj    = (float*)d_out;
  float* labels = (float*)d_out + PAIRS;

  dim3 blk(256);

  cast_all<<<dim3(680), blk, 0, stream>>>(W_er, W_nr, Wm, Wl1, Wi, Wh, Wro,
                                          Wer8, Wnr8, Wev8, Whw8, Wl18, Wi8, Wh8, Wro8);
  xp_xph16<<<dim3(64), blk, 0, stream>>>(nf, Wnr8, b_nr, Whw8, Xp, Xpf, XpH);
  e0_sm<<<dim3(PAIRS / 64), blk, 0, stream>>>(ef, Wer8, b_er, Wl18, Wev8,
                                              bl1, Wl2, bl2, XpH, bm,
                                              S1, Mpreh);
  attn2_ms<<<dim3(PAIRS / 64), blk, 0, stream>>>(Mpreh, S1, Wl18, bl1, Wl2, bl2,
                                                 adj, xf);
  gigh16<<<dim3(64, 6), blk, 0, stream>>>(xf, Xpf, Wi8, Wh8, bi, bh, gi, gh);
  labels_gru16<<<dim3(64, 3), blk, 0, stream>>>(gi, gh, Xp, Wro8, bro, labels);
}

// Round 14
// 210.648 us; speedup vs baseline: 1.5040x; 1.0588x over previous
//
#include <hip/hip_runtime.h>
#include <cmath>

namespace {

using f16 = _Float16;
typedef f16 f16x8 __attribute__((ext_vector_type(8)));
typedef f16 f16x4 __attribute__((ext_vector_type(4)));
typedef __fp16 h16x2 __attribute__((ext_vector_type(2)));
typedef float f32x4 __attribute__((ext_vector_type(4)));

constexpr int FE = 1216, FN = 1108, MD = 256, KC = 600;
constexpr int PAIRS = 65536, ROWS = 1024;

// workspace offsets (float units, all 16B-aligned)
constexpr size_t OFF_XP    = 0;                       // fp32 [1024][256]
constexpr size_t OFF_XPF   = OFF_XP    + 262144;      // f16  [1024][256]
constexpr size_t OFF_XPH   = OFF_XPF   + 131072;      // fp32 [1024][256]
constexpr size_t OFF_S1    = OFF_XPH   + 262144;      // fp32 [65536]
constexpr size_t OFF_S2    = OFF_S1    + 65536;       // (unused)
constexpr size_t OFF_XF    = OFF_S2    + 65536;       // f16  [1024][256]
constexpr size_t OFF_GI    = OFF_XF    + 131072;      // fp32 [1024][768]
constexpr size_t OFF_GH    = OFF_GI    + 786432;      // fp32 [1024][768]
constexpr size_t OFF_HNF   = OFF_GH    + 786432;      // (unused)
constexpr size_t OFF_WER8  = OFF_HNF   + 131072;      // f16 prefrag 152*256*8
constexpr size_t OFF_WNR8  = OFF_WER8  + 155648;      // 144*256*8
constexpr size_t OFF_WEV8  = OFF_WNR8  + 147456;      // 32*256*8
constexpr size_t OFF_WHW8  = OFF_WEV8  + 32768;       // 32*256*8
constexpr size_t OFF_WL18  = OFF_WHW8  + 32768;       // 32*256*8
constexpr size_t OFF_WI8   = OFF_WL18  + 32768;       // 32*768*8
constexpr size_t OFF_WH8   = OFF_WI8   + 98304;       // 32*768*8
constexpr size_t OFF_WRO8  = OFF_WH8   + 98304;       // 32*768*8 (KC pad 768)
constexpr size_t OFF_E0H   = OFF_WRO8  + 98304;       // (unused)
constexpr size_t OFF_MPREH = OFF_E0H   + 8388608;     // f16 [65536][256]

__device__ __forceinline__ float sigmoidf_(float x) { return 1.0f / (1.0f + expf(-x)); }

__device__ __forceinline__ void dma16(const void* g, void* l) {
  __builtin_amdgcn_global_load_lds((const unsigned int*)g, (unsigned int*)l, 16, 0, 0);
}

__device__ __forceinline__ f16x8 cvtp(f32x4 a, f32x4 b) {
  union { h16x2 q[4]; f16x8 h; } u;
  u.q[0] = __builtin_amdgcn_cvt_pkrtz(a[0], a[1]);
  u.q[1] = __builtin_amdgcn_cvt_pkrtz(a[2], a[3]);
  u.q[2] = __builtin_amdgcn_cvt_pkrtz(b[0], b[1]);
  u.q[3] = __builtin_amdgcn_cvt_pkrtz(b[2], b[3]);
  return u.h;
}

__device__ __forceinline__ f16x4 cvtp4(const float4& g) {
  union { h16x2 q[2]; f16x4 h; } u;
  u.q[0] = __builtin_amdgcn_cvt_pkrtz(g.x, g.y);
  u.q[1] = __builtin_amdgcn_cvt_pkrtz(g.z, g.w);
  return u.h;
}

// ---------------------------------------------------------------------------
// cast_all: prefragment all weight matrices into f16 MFMA-B layout
// ---------------------------------------------------------------------------
__global__ __launch_bounds__(256) void cast_all(
    const float* __restrict__ W_er, const float* __restrict__ W_nr,
    const float* __restrict__ Wm,   const float* __restrict__ Wl1,
    const float* __restrict__ Wi,   const float* __restrict__ Wh,
    const float* __restrict__ Wro,
    f16* __restrict__ Wer8, f16* __restrict__ Wnr8, f16* __restrict__ Wev8,
    f16* __restrict__ Whw8, f16* __restrict__ Wl18, f16* __restrict__ Wi8,
    f16* __restrict__ Wh8,  f16* __restrict__ Wro8)
{
  int b = blockIdx.x, t = threadIdx.x;
  const float* W; f16* out; int ldw, koff, K, N, Npad, kc, nb;
  if (b < 152)      { W=W_er; out=Wer8; ldw=FE;  koff=0;   K=FE;  N=256; Npad=256; kc=b;     nb=0; }
  else if (b < 296) { b-=152; W=W_nr; out=Wnr8; ldw=FN;  koff=0;   K=FN;  N=256; Npad=256; kc=b; nb=0; }
  else if (b < 328) { b-=296; W=Wm;   out=Wev8; ldw=512; koff=256; K=256; N=256; Npad=256; kc=b; nb=0; }
  else if (b < 360) { b-=328; W=Wm;   out=Whw8; ldw=512; koff=0;   K=256; N=256; Npad=256; kc=b; nb=0; }
  else if (b < 392) { b-=360; W=Wl1;  out=Wl18; ldw=256; koff=0;   K=256; N=256; Npad=256; kc=b; nb=0; }
  else if (b < 488) { b-=392; W=Wi;   out=Wi8;  ldw=256; koff=0;   K=256; N=768; Npad=768; kc=b&31; nb=(b>>5)*256; }
  else if (b < 584) { b-=488; W=Wh;   out=Wh8;  ldw=256; koff=0;   K=256; N=768; Npad=768; kc=b&31; nb=(b>>5)*256; }
  else              { b-=584; W=Wro;  out=Wro8; ldw=256; koff=0;   K=256; N=600; Npad=768; kc=b&31; nb=(b>>5)*256; }
  int n = nb + t;
  if (n >= Npad) return;
  f16x8 h;
#pragma unroll
  for (int j = 0; j < 8; ++j) {
    int k = kc * 8 + j;
    float v = (k < K && n < N) ? W[(size_t)n * ldw + koff + k] : 0.0f;
    h[j] = (f16)v;
  }
  *reinterpret_cast<f16x8*>(out + ((size_t)kc * Npad + n) * 8) = h;
}

// ---------------------------------------------------------------------------
// Fused E0 + score-1 + Mpre.  BK=64 fp32 chunks (256 B/row/chunk -> 2x fewer
// DRAM page activations than BK=32), 3x16KB DMA ring, counted vmcnt(4),
// B via preloaded vector loads. Then T tile; S pass; M pass; Mpre out.
// ---------------------------------------------------------------------------
__global__ __launch_bounds__(256, 3) void e0_sm(
    const float* __restrict__ A, const f16* __restrict__ Ber,
    const float* __restrict__ b_er,
    const f16* __restrict__ Bl1, const f16* __restrict__ Bev,
    const float* __restrict__ bl1, const float* __restrict__ Wl2,
    const float* __restrict__ bl2,
    const float* __restrict__ XpH, const float* __restrict__ bm,
    float* __restrict__ S1, f16* __restrict__ Mpreh)
{
  const int tid = threadIdx.x;
  const int wave = tid >> 6, l = tid & 63;
  const int lo = l & 15, hi = l >> 4;
  const int wcol = wave * 64;
  alignas(16) __shared__ char sm[49152];   // 3x16KB ring; first 32KB reused as T
  __shared__ float red[64][4];
  const size_t arow0 = (size_t)blockIdx.x * 64;

  // ---------------- phase E0 ----------------
  {
    f32x4 acc[4][4] = {};
    // A DMA (4 instr/wave/chunk): chunk = [64 rows][256 B]; dest linear;
    // source slot swizzled: phys slot s holds src slot s^(row&7)  (16B units)
    const char* asrc[4]; int adst[4];
#pragma unroll
    for (int j = 0; j < 4; ++j) {
      const int row = wave*16 + j*4 + (l >> 4);
      const int slot = (l & 15) ^ (row & 7);
      asrc[j] = (const char*)(A + (arow0 + row) * FE) + slot * 16;
      adst[j] = wave*4096 + j*1024 + l*16;
    }

#define CH_ISSUE(P)                                                           \
    { char* bb = sm + (P)*16384;                                              \
      dma16(asrc[0], bb + adst[0]); asrc[0] += 256;                           \
      dma16(asrc[1], bb + adst[1]); asrc[1] += 256;                           \
      dma16(asrc[2], bb + adst[2]); asrc[2] += 256;                           \
      dma16(asrc[3], bb + adst[3]); asrc[3] += 256; }

    CH_ISSUE(0)
    CH_ISSUE(1)

    for (int t = 0; t < 19; ++t) {
      if (t < 18) { asm volatile("s_waitcnt vmcnt(4)" ::: "memory"); }
      else        { asm volatile("s_waitcnt vmcnt(0)" ::: "memory"); }
      __builtin_amdgcn_sched_barrier(0);
      __builtin_amdgcn_s_barrier();
      __builtin_amdgcn_sched_barrier(0);

      // B preload BEFORE next DMA issue
      f16x8 bf0[4], bf1[4];
#pragma unroll
      for (int n = 0; n < 4; ++n) {
        const int kc0 = t*8 + 0*4 + hi;
        const int kc1 = t*8 + 1*4 + hi;
        bf0[n] = *reinterpret_cast<const f16x8*>(Ber + ((size_t)kc0*256 + (wcol + n*16 + lo)) * 8);
        bf1[n] = *reinterpret_cast<const f16x8*>(Ber + ((size_t)kc1*256 + (wcol + n*16 + lo)) * 8);
      }
      __builtin_amdgcn_sched_barrier(0);
      if (t < 17) { CH_ISSUE((t + 2) % 3) }
      __builtin_amdgcn_sched_barrier(0);

      const char* Ab = sm + (t % 3) * 16384;
#pragma unroll
      for (int ks = 0; ks < 2; ++ks) {
        f16x8 af[4];
#pragma unroll
        for (int m = 0; m < 4; ++m) {
          const int r = m*16 + lo;
          const int s0 = (ks*8 + hi*2)     ^ (r & 7);
          const int s1 = (ks*8 + hi*2 + 1) ^ (r & 7);
          f32x4 a0 = *reinterpret_cast<const f32x4*>(Ab + r*256 + s0*16);
          f32x4 a1 = *reinterpret_cast<const f32x4*>(Ab + r*256 + s1*16);
          af[m] = cvtp(a0, a1);
        }
#pragma unroll
        for (int m = 0; m < 4; ++m)
#pragma unroll
          for (int n = 0; n < 4; ++n)
            acc[m][n] = __builtin_amdgcn_mfma_f32_16x16x32_f16(
                af[m], ks == 0 ? bf0[n] : bf1[n], acc[m][n], 0, 0, 0);
      }
    }
#undef CH_ISSUE

    __syncthreads();     // ring dead -> reuse first 32KB as T
    // E0 tile -> T (f16, swizzled 512B rows)
#pragma unroll
    for (int m = 0; m < 4; ++m)
#pragma unroll
      for (int n = 0; n < 4; ++n) {
        const int col = wcol + n*16 + lo;
        const float bb = b_er[col];
#pragma unroll
        for (int r = 0; r < 4; ++r) {
          const int rl = m*16 + hi*4 + r;
          const int byte = rl*512 + ((col*2) ^ ((rl & 7) << 4));
          *reinterpret_cast<f16*>(sm + byte) = (f16)(acc[m][n][r] + bb);
        }
      }
  }
  __syncthreads();

  // ---------------- pass S: accS = T @ Wl1^T ----------------
  {
    f32x4 accS[4][4] = {};
    for (int t = 0; t < 4; ++t) {
#pragma unroll
      for (int ks = 0; ks < 2; ++ks) {
        const int kc = t*8 + ks*4 + hi;
        const int b0 = t*128 + ks*64 + hi*16;
        f16x8 af[4], bf[4];
#pragma unroll
        for (int m = 0; m < 4; ++m) {
          const int r = m*16 + lo;
          af[m] = *reinterpret_cast<const f16x8*>(sm + r*512 + (b0 ^ ((r & 7) << 4)));
        }
#pragma unroll
        for (int n = 0; n < 4; ++n)
          bf[n] = *reinterpret_cast<const f16x8*>(Bl1 + ((size_t)kc*256 + (wcol + n*16 + lo)) * 8);
#pragma unroll
        for (int m = 0; m < 4; ++m)
#pragma unroll
          for (int n = 0; n < 4; ++n)
            accS[m][n] = __builtin_amdgcn_mfma_f32_16x16x32_f16(af[m], bf[n], accS[m][n], 0, 0, 0);
      }
    }
#pragma unroll
    for (int m = 0; m < 4; ++m) {
#pragma unroll
      for (int r = 0; r < 4; ++r) {
        float p = 0.f;
#pragma unroll
        for (int n = 0; n < 4; ++n) {
          const int col = wcol + n*16 + lo;
          p += Wl2[col] * fmaxf(accS[m][n][r] + bl1[col], 0.0f);
        }
        p += __shfl_xor(p, 1); p += __shfl_xor(p, 2);
        p += __shfl_xor(p, 4); p += __shfl_xor(p, 8);
        if (lo == 0) red[m*16 + hi*4 + r][wave] = p;
      }
    }
  }

  // ---------------- pass M: accM = T @ Wev^T ----------------
  {
    f32x4 accM[4][4] = {};
    for (int t = 0; t < 4; ++t) {
#pragma unroll
      for (int ks = 0; ks < 2; ++ks) {
        const int kc = t*8 + ks*4 + hi;
        const int b0 = t*128 + ks*64 + hi*16;
        f16x8 af[4], bf[4];
#pragma unroll
        for (int m = 0; m < 4; ++m) {
          const int r = m*16 + lo;
          af[m] = *reinterpret_cast<const f16x8*>(sm + r*512 + (b0 ^ ((r & 7) << 4)));
        }
#pragma unroll
        for (int n = 0; n < 4; ++n)
          bf[n] = *reinterpret_cast<const f16x8*>(Bev + ((size_t)kc*256 + (wcol + n*16 + lo)) * 8);
#pragma unroll
        for (int m = 0; m < 4; ++m)
#pragma unroll
          for (int n = 0; n < 4; ++n)
            accM[m][n] = __builtin_amdgcn_mfma_f32_16x16x32_f16(af[m], bf[n], accM[m][n], 0, 0, 0);
      }
    }
    __syncthreads();   // all T reads done; overwrite with Mpre (linear)
    const int rxb = (blockIdx.x >> 6) * 64;
#pragma unroll
    for (int m = 0; m < 4; ++m)
#pragma unroll
      for (int n = 0; n < 4; ++n) {
        const int col = wcol + n*16 + lo;
        const float bb = bm[col];
#pragma unroll
        for (int r = 0; r < 4; ++r) {
          const int rl = m*16 + hi*4 + r;
          float v = accM[m][n][r] + XpH[(size_t)(rxb + rl)*256 + col] + bb;
          *reinterpret_cast<f16*>(sm + rl*512 + col*2) = (f16)fmaxf(v, 0.0f);
        }
      }
  }
  __syncthreads();
#pragma unroll
  for (int i = 0; i < 8; ++i) {
    const int lin = i*4096 + tid*16;
    f16x8 v = *reinterpret_cast<const f16x8*>(sm + lin);
    *reinterpret_cast<f16x8*>((char*)Mpreh + arow0*512 + lin) = v;
  }
  if (tid < 64)
    S1[arow0 + tid] = sigmoidf_(bl2[0] + red[tid][0] + red[tid][1] + red[tid][2] + red[tid][3]);
}

// ---------------------------------------------------------------------------
// Score pass 2 (transposed gather, reg-staged) + fused msum.
// ---------------------------------------------------------------------------
__global__ __launch_bounds__(256) void attn2_ms(
    const f16* __restrict__ Mpreh, const float* __restrict__ S1,
    const f16* __restrict__ Bl1, const float* __restrict__ bl1,
    const float* __restrict__ Wl2, const float* __restrict__ bl2,
    float* __restrict__ adj, f16* __restrict__ xf)
{
  const int blk = blockIdx.x;
  const int b = blk >> 6, v = blk & 63;
  const int tid = threadIdx.x;
  const int wave = tid >> 6, l = tid & 63;
  const int lo = l & 15, hi = l >> 4;
  const int wcol = wave * 64;
  __shared__ f16 As[2][64][72];
  __shared__ float red[64][4];
  __shared__ float s1s[64];
  __shared__ float s2s[64];
  f32x4 acc[4][4] = {};
  const int rr0 = tid >> 3, part = tid & 7;
  const size_t pbase = (size_t)b * 4096 + v;
  f16x8 ga, gb;

  if (tid < 64) s1s[tid] = S1[pbase + (size_t)tid * 64];
  __syncthreads();

#define A2_LOAD(T)                                                              \
  { ga = *reinterpret_cast<const f16x8*>(Mpreh + (pbase + (size_t)rr0*64)*256 + (T)*64 + part*8);     \
    gb = *reinterpret_cast<const f16x8*>(Mpreh + (pbase + (size_t)(rr0+32)*64)*256 + (T)*64 + part*8); }
#define A2_WRITE(BUF)                                                           \
  { f16 sa = (f16)s1s[rr0], sb = (f16)s1s[rr0 + 32];                            \
    f16x8 ha = ga, hb = gb;                                                     \
    _Pragma("unroll") for (int j = 0; j < 8; ++j) { ha[j] *= sa; hb[j] *= sb; } \
    *reinterpret_cast<f16x8*>(&As[BUF][rr0][part*8]) = ha;                      \
    *reinterpret_cast<f16x8*>(&As[BUF][rr0 + 32][part*8]) = hb; }

  A2_LOAD(0); A2_WRITE(0);
  for (int t = 0; t < 4; ++t) {
    __syncthreads();
    if (t < 3) A2_LOAD(t + 1);
    const int cur = t & 1;
#pragma unroll
    for (int ks = 0; ks < 2; ++ks) {
      f16x8 af[4], bf[4];
      const int kc = t*8 + ks*4 + hi;
#pragma unroll
      for (int m = 0; m < 4; ++m)
        af[m] = *reinterpret_cast<const f16x8*>(&As[cur][m*16 + lo][ks*32 + hi*8]);
#pragma unroll
      for (int n = 0; n < 4; ++n)
        bf[n] = *reinterpret_cast<const f16x8*>(Bl1 + ((size_t)kc*256 + (wcol + n*16 + lo)) * 8);
#pragma unroll
      for (int m = 0; m < 4; ++m)
#pragma unroll
        for (int n = 0; n < 4; ++n)
          acc[m][n] = __builtin_amdgcn_mfma_f32_16x16x32_f16(af[m], bf[n], acc[m][n], 0, 0, 0);
    }
    if (t < 3) A2_WRITE(cur ^ 1);
  }
#undef A2_LOAD
#undef A2_WRITE
#pragma unroll
  for (int m = 0; m < 4; ++m) {
#pragma unroll
    for (int r = 0; r < 4; ++r) {
      float p = 0.f;
#pragma unroll
      for (int n = 0; n < 4; ++n) {
        const int col = wcol + n*16 + lo;
        p += Wl2[col] * fmaxf(acc[m][n][r] + bl1[col], 0.0f);
      }
      p += __shfl_xor(p, 1); p += __shfl_xor(p, 2);
      p += __shfl_xor(p, 4); p += __shfl_xor(p, 8);
      if (lo == 0) red[m*16 + hi*4 + r][wave] = p;
    }
  }
  __syncthreads();
  if (tid < 64) {
    float s = bl2[0] + red[tid][0] + red[tid][1] + red[tid][2] + red[tid][3];
    adj[(size_t)b*4096 + (size_t)v*64 + tid] = s;
    s2s[tid] = sigmoidf_(s);
  }
  __syncthreads();
  const int c = tid;
  const f16* mp = Mpreh + (size_t)blk * 64 * 256 + c;
  float accx = 0.f;
#pragma unroll 8
  for (int w = 0; w < 64; ++w)
    accx += (float)mp[(size_t)w * 256] * s2s[w];
  xf[(size_t)blk * 256 + c] = (f16)accx;
}

// ---------------------------------------------------------------------------
// Fused Xp + XpH, BM=16, grid 64
// ---------------------------------------------------------------------------
__global__ __launch_bounds__(256) void xp_xph16(
    const float* __restrict__ A, const f16* __restrict__ Bnr,
    const float* __restrict__ b_nr, const f16* __restrict__ Bhw,
    float* __restrict__ Xp, f16* __restrict__ Xpf, float* __restrict__ XpH)
{
  const int tid = threadIdx.x;
  const int wave = tid >> 6, l = tid & 63;
  const int lo = l & 15, hi = l >> 4;
  const int wcol = wave * 64;
  __shared__ f16 As[2][16][72];
  __shared__ f16 XpS[16][264];
  f32x4 acc[4] = {};
  const size_t arow0 = (size_t)blockIdx.x * 16;
  const int srow = tid >> 4, spart = tid & 15;
  const float* abase = A + (arow0 + srow) * FN;
  float4 g;
  const float4 z4 = make_float4(0.f, 0.f, 0.f, 0.f);

#define XQ_LOAD(T)                                                          \
  { int kb = (T)*64 + spart*4;                                              \
    g = (kb + 4 <= FN) ? *(const float4*)(abase + kb) : z4; }
#define XQ_WRITE(BUF)                                                       \
  { *reinterpret_cast<f16x4*>(&As[BUF][srow][spart*4]) = cvtp4(g); }

  XQ_LOAD(0); XQ_WRITE(0);
  for (int t = 0; t < 18; ++t) {
    __syncthreads();
    if (t < 17) XQ_LOAD(t + 1);
    const int cur = t & 1;
#pragma unroll
    for (int ks = 0; ks < 2; ++ks) {
      const int kc = t*8 + ks*4 + hi;
      f16x8 af = *reinterpret_cast<const f16x8*>(&As[cur][lo][ks*32 + hi*8]);
      f16x8 bf[4];
#pragma unroll
      for (int n = 0; n < 4; ++n)
        bf[n] = *reinterpret_cast<const f16x8*>(Bnr + ((size_t)kc*256 + (wcol + n*16 + lo)) * 8);
#pragma unroll
      for (int n = 0; n < 4; ++n)
        acc[n] = __builtin_amdgcn_mfma_f32_16x16x32_f16(af, bf[n], acc[n], 0, 0, 0);
    }
    if (t < 17) XQ_WRITE(cur ^ 1);
  }
#undef XQ_LOAD
#undef XQ_WRITE
#pragma unroll
  for (int n = 0; n < 4; ++n) {
    const int col = wcol + n*16 + lo;
    const float bb = b_nr[col];
#pragma unroll
    for (int r = 0; r < 4; ++r) {
      const size_t row = arow0 + hi*4 + r;
      float v = acc[n][r] + bb;
      Xp[row * 256 + col] = v;
      f16 hv = (f16)v;
      Xpf[row * 256 + col] = hv;
      XpS[hi*4 + r][col] = hv;
    }
  }
  __syncthreads();
  f32x4 acch[4] = {};
  for (int t = 0; t < 4; ++t) {
#pragma unroll
    for (int ks = 0; ks < 2; ++ks) {
      const int kc = t*8 + ks*4 + hi;
      f16x8 af = *reinterpret_cast<const f16x8*>(&XpS[lo][t*64 + ks*32 + hi*8]);
      f16x8 bf[4];
#pragma unroll
      for (int n = 0; n < 4; ++n)
        bf[n] = *reinterpret_cast<const f16x8*>(Bhw + ((size_t)kc*256 + (wcol + n*16 + lo)) * 8);
#pragma unroll
      for (int n = 0; n < 4; ++n)
        acch[n] = __builtin_amdgcn_mfma_f32_16x16x32_f16(af, bf[n], acch[n], 0, 0, 0);
    }
  }
#pragma unroll
  for (int n = 0; n < 4; ++n) {
    const int col = wcol + n*16 + lo;
#pragma unroll
    for (int r = 0; r < 4; ++r)
      XpH[(arow0 + hi*4 + r) * 256 + col] = acch[n][r];
  }
}

// ---------------------------------------------------------------------------
// Merged gi/gh GEMM, BM=16: grid (64, 6)
// ---------------------------------------------------------------------------
__global__ __launch_bounds__(256) void gigh16(
    const f16* __restrict__ xf, const f16* __restrict__ Xpf,
    const f16* __restrict__ Wi8, const f16* __restrict__ Wh8,
    const float* __restrict__ bi, const float* __restrict__ bh,
    float* __restrict__ gi, float* __restrict__ gh)
{
  const int rb = blockIdx.x;
  int cb = blockIdx.y;
  const f16* A; const f16* Bp; const float* bias; float* C;
  if (cb < 3) { A = xf;  Bp = Wi8; bias = bi; C = gi; }
  else        { A = Xpf; Bp = Wh8; bias = bh; C = gh; cb -= 3; }
  const int tid = threadIdx.x;
  const int wave = tid >> 6, l = tid & 63;
  const int lo = l & 15, hi = l >> 4;
  const int wcol = cb * 256 + wave * 64;
  __shared__ f16 As[16][264];
  f32x4 acc[4] = {};
  const size_t arow0 = (size_t)rb * 16;

#pragma unroll
  for (int i = 0; i < 2; ++i) {
    int idx = i * 256 + tid;
    int rr = idx >> 5, part = idx & 31;
    *reinterpret_cast<f16x8*>(&As[rr][part*8]) =
        *reinterpret_cast<const f16x8*>(A + (arow0 + rr)*256 + part*8);
  }
  __syncthreads();

  for (int t = 0; t < 4; ++t) {
#pragma unroll
    for (int ks = 0; ks < 2; ++ks) {
      const int kc = t*8 + ks*4 + hi;
      f16x8 af = *reinterpret_cast<const f16x8*>(&As[lo][t*64 + ks*32 + hi*8]);
      f16x8 bf[4];
#pragma unroll
      for (int n = 0; n < 4; ++n)
        bf[n] = *reinterpret_cast<const f16x8*>(Bp + ((size_t)kc*768 + (wcol + n*16 + lo)) * 8);
#pragma unroll
      for (int n = 0; n < 4; ++n)
        acc[n] = __builtin_amdgcn_mfma_f32_16x16x32_f16(af, bf[n], acc[n], 0, 0, 0);
    }
  }
#pragma unroll
  for (int n = 0; n < 4; ++n) {
    const int col = wcol + n*16 + lo;
    const float bb = bias[col];
#pragma unroll
    for (int r = 0; r < 4; ++r)
      C[(arow0 + hi*4 + r) * 768 + col] = acc[n][r] + bb;
  }
}

// ---------------------------------------------------------------------------
// Labels GEMM with GRU fused into staging, BM=16: grid (64, 3)
// ---------------------------------------------------------------------------
__global__ __launch_bounds__(256) void labels_gru16(
    const float* __restrict__ gi, const float* __restrict__ gh,
    const float* __restrict__ Xp, const f16* __restrict__ Wro8,
    const float* __restrict__ bro, float* __restrict__ labels)
{
  const int rb = blockIdx.x, cb = blockIdx.y;
  const int tid = threadIdx.x;
  const int wave = tid >> 6, l = tid & 63;
  const int lo = l & 15, hi = l >> 4;
  const int wcol = cb * 256 + wave * 64;
  __shared__ f16 As[16][264];
  f32x4 acc[4] = {};
  const size_t arow0 = (size_t)rb * 16;

  {
    const int rr = tid >> 4, c0 = (tid & 15) * 16;
    const float* gir = gi + (arow0 + rr) * 768;
    const float* ghr = gh + (arow0 + rr) * 768;
    const float* xpr = Xp + (arow0 + rr) * 256;
#pragma unroll
    for (int j = 0; j < 16; ++j) {
      const int c = c0 + j;
      float r = sigmoidf_(gir[c] + ghr[c]);
      float z = sigmoidf_(gir[256 + c] + ghr[256 + c]);
      float n = tanhf(gir[512 + c] + r * ghr[512 + c]);
      float h = xpr[c];
      As[rr][c] = (f16)((1.0f - z) * n + z * h);
    }
  }
  __syncthreads();

  for (int t = 0; t < 4; ++t) {
#pragma unroll
    for (int ks = 0; ks < 2; ++ks) {
      const int kc = t*8 + ks*4 + hi;
      f16x8 af = *reinterpret_cast<const f16x8*>(&As[lo][t*64 + ks*32 + hi*8]);
      f16x8 bf[4];
#pragma unroll
      for (int n = 0; n < 4; ++n)
        bf[n] = *reinterpret_cast<const f16x8*>(Wro8 + ((size_t)kc*768 + (wcol + n*16 + lo)) * 8);
#pragma unroll
      for (int n = 0; n < 4; ++n)
        acc[n] = __builtin_amdgcn_mfma_f32_16x16x32_f16(af, bf[n], acc[n], 0, 0, 0);
    }
  }
#pragma unroll
  for (int n = 0; n < 4; ++n) {
    const int col = wcol + n*16 + lo;
    if (col < KC) {
      const float bb = bro[col];
#pragma unroll
      for (int r = 0; r < 4; ++r)
        labels[(arow0 + hi*4 + r) * (size_t)KC + col] = acc[n][r] + bb;
    }
  }
}

} // namespace

extern "C" void kernel_launch(void* const* d_in, const int* in_sizes, int n_in,
                              void* d_out, int out_size, void* d_ws, size_t ws_size,
                              hipStream_t stream)
{
  const float* ef   = (const float*)d_in[0];
  const float* nf   = (const float*)d_in[1];
  const float* W_er = (const float*)d_in[7];
  const float* b_er = (const float*)d_in[8];
  const float* W_nr = (const float*)d_in[9];
  const float* b_nr = (const float*)d_in[10];
  const float* Wl1  = (const float*)d_in[11];
  const float* bl1  = (const float*)d_in[12];
  const float* Wl2  = (const float*)d_in[13];
  const float* bl2  = (const float*)d_in[14];
  const float* Wm   = (const float*)d_in[15];
  const float* bm   = (const float*)d_in[16];
  const float* Wi   = (const float*)d_in[17];
  const float* bi   = (const float*)d_in[18];
  const float* Wh   = (const float*)d_in[19];
  const float* bh   = (const float*)d_in[20];
  const float* Wro  = (const float*)d_in[21];
  const float* bro  = (const float*)d_in[22];

  float* ws = (float*)d_ws;
  float* Xp    = ws + OFF_XP;
  f16*   Xpf   = (f16*)(ws + OFF_XPF);
  float* XpH   = ws + OFF_XPH;
  float* S1    = ws + OFF_S1;
  f16*   xf    = (f16*)(ws + OFF_XF);
  float* gi    = ws + OFF_GI;
  float* gh    = ws + OFF_GH;
  f16*   Wer8  = (f16*)(ws + OFF_WER8);
  f16*   Wnr8  = (f16*)(ws + OFF_WNR8);
  f16*   Wev8  = (f16*)(ws + OFF_WEV8);
  f16*   Whw8  = (f16*)(ws + OFF_WHW8);
  f16*   Wl18  = (f16*)(ws + OFF_WL18);
  f16*   Wi8   = (f16*)(ws + OFF_WI8);
  f16*   Wh8   = (f16*)(ws + OFF_WH8);
  f16*   Wro8  = (f16*)(ws + OFF_WRO8);
  f16*   Mpreh = (f16*)(ws + OFF_MPREH);
  float* adj    = (float*)d_out;
  float* labels = (float*)d_out + PAIRS;

  dim3 blk(256);

  cast_all<<<dim3(680), blk, 0, stream>>>(W_er, W_nr, Wm, Wl1, Wi, Wh, Wro,
                                          Wer8, Wnr8, Wev8, Whw8, Wl18, Wi8, Wh8, Wro8);
  xp_xph16<<<dim3(64), blk, 0, stream>>>(nf, Wnr8, b_nr, Whw8, Xp, Xpf, XpH);
  e0_sm<<<dim3(PAIRS / 64), blk, 0, stream>>>(ef, Wer8, b_er, Wl18, Wev8,
                                              bl1, Wl2, bl2, XpH, bm,
                                              S1, Mpreh);
  attn2_ms<<<dim3(PAIRS / 64), blk, 0, stream>>>(Mpreh, S1, Wl18, bl1, Wl2, bl2,
                                                 adj, xf);
  gigh16<<<dim3(64, 6), blk, 0, stream>>>(xf, Xpf, Wi8, Wh8, bi, bh, gi, gh);
  labels_gru16<<<dim3(64, 3), blk, 0, stream>>>(gi, gh, Xp, Wro8, bro, labels);
}

// Round 15
// 195.656 us; speedup vs baseline: 1.6193x; 1.0766x over previous
//
#include <hip/hip_runtime.h>
#include <cmath>

namespace {

using f16 = _Float16;
typedef f16 f16x8 __attribute__((ext_vector_type(8)));
typedef f16 f16x4 __attribute__((ext_vector_type(4)));
typedef __fp16 h16x2 __attribute__((ext_vector_type(2)));
typedef float f32x4 __attribute__((ext_vector_type(4)));

constexpr int FE = 1216, FN = 1108, MD = 256, KC = 600;
constexpr int PAIRS = 65536, ROWS = 1024;

// workspace offsets (float units, all 16B-aligned)
constexpr size_t OFF_XP    = 0;                       // fp32 [1024][256]
constexpr size_t OFF_XPF   = OFF_XP    + 262144;      // f16  [1024][256]
constexpr size_t OFF_XPH   = OFF_XPF   + 131072;      // fp32 [1024][256]
constexpr size_t OFF_S1    = OFF_XPH   + 262144;      // fp32 [65536]
constexpr size_t OFF_S2    = OFF_S1    + 65536;       // (unused)
constexpr size_t OFF_XF    = OFF_S2    + 65536;       // f16  [1024][256]
constexpr size_t OFF_GI    = OFF_XF    + 131072;      // fp32 [1024][768]
constexpr size_t OFF_GH    = OFF_GI    + 786432;      // fp32 [1024][768]
constexpr size_t OFF_HNF   = OFF_GH    + 786432;      // (unused)
constexpr size_t OFF_WER8  = OFF_HNF   + 131072;      // f16 prefrag 152*256*8
constexpr size_t OFF_WNR8  = OFF_WER8  + 155648;      // 144*256*8
constexpr size_t OFF_WEV8  = OFF_WNR8  + 147456;      // 32*256*8
constexpr size_t OFF_WHW8  = OFF_WEV8  + 32768;       // 32*256*8
constexpr size_t OFF_WL18  = OFF_WHW8  + 32768;       // 32*256*8
constexpr size_t OFF_WI8   = OFF_WL18  + 32768;       // 32*768*8
constexpr size_t OFF_WH8   = OFF_WI8   + 98304;       // 32*768*8
constexpr size_t OFF_WRO8  = OFF_WH8   + 98304;       // 32*768*8 (KC pad 768)
constexpr size_t OFF_E0H   = OFF_WRO8  + 98304;       // (unused)
constexpr size_t OFF_MPREH = OFF_E0H   + 8388608;     // f16 [65536][256]

__device__ __forceinline__ float sigmoidf_(float x) { return 1.0f / (1.0f + expf(-x)); }

__device__ __forceinline__ void dma16(const void* g, void* l) {
  __builtin_amdgcn_global_load_lds((const unsigned int*)g, (unsigned int*)l, 16, 0, 0);
}

__device__ __forceinline__ f16x8 cvtp(f32x4 a, f32x4 b) {
  union { h16x2 q[4]; f16x8 h; } u;
  u.q[0] = __builtin_amdgcn_cvt_pkrtz(a[0], a[1]);
  u.q[1] = __builtin_amdgcn_cvt_pkrtz(a[2], a[3]);
  u.q[2] = __builtin_amdgcn_cvt_pkrtz(b[0], b[1]);
  u.q[3] = __builtin_amdgcn_cvt_pkrtz(b[2], b[3]);
  return u.h;
}

__device__ __forceinline__ f16x4 cvtp4(const float4& g) {
  union { h16x2 q[2]; f16x4 h; } u;
  u.q[0] = __builtin_amdgcn_cvt_pkrtz(g.x, g.y);
  u.q[1] = __builtin_amdgcn_cvt_pkrtz(g.z, g.w);
  return u.h;
}

// ---------------------------------------------------------------------------
// cast_all: prefragment all weight matrices into f16 MFMA-B layout
// ---------------------------------------------------------------------------
__global__ __launch_bounds__(256) void cast_all(
    const float* __restrict__ W_er, const float* __restrict__ W_nr,
    const float* __restrict__ Wm,   const float* __restrict__ Wl1,
    const float* __restrict__ Wi,   const float* __restrict__ Wh,
    const float* __restrict__ Wro,
    f16* __restrict__ Wer8, f16* __restrict__ Wnr8, f16* __restrict__ Wev8,
    f16* __restrict__ Whw8, f16* __restrict__ Wl18, f16* __restrict__ Wi8,
    f16* __restrict__ Wh8,  f16* __restrict__ Wro8)
{
  int b = blockIdx.x, t = threadIdx.x;
  const float* W; f16* out; int ldw, koff, K, N, Npad, kc, nb;
  if (b < 152)      { W=W_er; out=Wer8; ldw=FE;  koff=0;   K=FE;  N=256; Npad=256; kc=b;     nb=0; }
  else if (b < 296) { b-=152; W=W_nr; out=Wnr8; ldw=FN;  koff=0;   K=FN;  N=256; Npad=256; kc=b; nb=0; }
  else if (b < 328) { b-=296; W=Wm;   out=Wev8; ldw=512; koff=256; K=256; N=256; Npad=256; kc=b; nb=0; }
  else if (b < 360) { b-=328; W=Wm;   out=Whw8; ldw=512; koff=0;   K=256; N=256; Npad=256; kc=b; nb=0; }
  else if (b < 392) { b-=360; W=Wl1;  out=Wl18; ldw=256; koff=0;   K=256; N=256; Npad=256; kc=b; nb=0; }
  else if (b < 488) { b-=392; W=Wi;   out=Wi8;  ldw=256; koff=0;   K=256; N=768; Npad=768; kc=b&31; nb=(b>>5)*256; }
  else if (b < 584) { b-=488; W=Wh;   out=Wh8;  ldw=256; koff=0;   K=256; N=768; Npad=768; kc=b&31; nb=(b>>5)*256; }
  else              { b-=584; W=Wro;  out=Wro8; ldw=256; koff=0;   K=256; N=600; Npad=768; kc=b&31; nb=(b>>5)*256; }
  int n = nb + t;
  if (n >= Npad) return;
  f16x8 h;
#pragma unroll
  for (int j = 0; j < 8; ++j) {
    int k = kc * 8 + j;
    float v = (k < K && n < N) ? W[(size_t)n * ldw + koff + k] : 0.0f;
    h[j] = (f16)v;
  }
  *reinterpret_cast<f16x8*>(out + ((size_t)kc * Npad + n) * 8) = h;
}

// ---------------------------------------------------------------------------
// Fused E0 + score-1 + Mpre (round-10 config + XCD-chunked block swizzle).
// BK=64 fp32 chunks, 3x16KB DMA ring, counted vmcnt(4), B via preloaded
// vector loads. Then T tile; S pass; M pass; Mpre out.
// ---------------------------------------------------------------------------
__global__ __launch_bounds__(256) void e0_sm(
    const float* __restrict__ A, const f16* __restrict__ Ber,
    const float* __restrict__ b_er,
    const f16* __restrict__ Bl1, const f16* __restrict__ Bev,
    const float* __restrict__ bl1, const float* __restrict__ Wl2,
    const float* __restrict__ bl2,
    const float* __restrict__ XpH, const float* __restrict__ bm,
    float* __restrict__ S1, f16* __restrict__ Mpreh)
{
  // XCD-chunked swizzle (T1): consecutive panels on the same XCD L2.
  // nwg = 1024 divisible by 8 -> bijective.
  const int blk = (blockIdx.x & 7) * 128 + (blockIdx.x >> 3);
  const int tid = threadIdx.x;
  const int wave = tid >> 6, l = tid & 63;
  const int lo = l & 15, hi = l >> 4;
  const int wcol = wave * 64;
  alignas(16) __shared__ char sm[49152];   // 3x16KB ring; first 32KB reused as T
  __shared__ float red[64][4];
  const size_t arow0 = (size_t)blk * 64;

  // ---------------- phase E0 ----------------
  {
    f32x4 acc[4][4] = {};
    const char* asrc[4]; int adst[4];
#pragma unroll
    for (int j = 0; j < 4; ++j) {
      const int row = wave*16 + j*4 + (l >> 4);
      const int slot = (l & 15) ^ (row & 7);
      asrc[j] = (const char*)(A + (arow0 + row) * FE) + slot * 16;
      adst[j] = wave*4096 + j*1024 + l*16;
    }

#define CH_ISSUE(P)                                                           \
    { char* bb = sm + (P)*16384;                                              \
      dma16(asrc[0], bb + adst[0]); asrc[0] += 256;                           \
      dma16(asrc[1], bb + adst[1]); asrc[1] += 256;                           \
      dma16(asrc[2], bb + adst[2]); asrc[2] += 256;                           \
      dma16(asrc[3], bb + adst[3]); asrc[3] += 256; }

    CH_ISSUE(0)
    CH_ISSUE(1)

    for (int t = 0; t < 19; ++t) {
      if (t < 18) { asm volatile("s_waitcnt vmcnt(4)" ::: "memory"); }
      else        { asm volatile("s_waitcnt vmcnt(0)" ::: "memory"); }
      __builtin_amdgcn_sched_barrier(0);
      __builtin_amdgcn_s_barrier();
      __builtin_amdgcn_sched_barrier(0);

      // B preload BEFORE next DMA issue
      f16x8 bf0[4], bf1[4];
#pragma unroll
      for (int n = 0; n < 4; ++n) {
        const int kc0 = t*8 + 0*4 + hi;
        const int kc1 = t*8 + 1*4 + hi;
        bf0[n] = *reinterpret_cast<const f16x8*>(Ber + ((size_t)kc0*256 + (wcol + n*16 + lo)) * 8);
        bf1[n] = *reinterpret_cast<const f16x8*>(Ber + ((size_t)kc1*256 + (wcol + n*16 + lo)) * 8);
      }
      __builtin_amdgcn_sched_barrier(0);
      if (t < 17) { CH_ISSUE((t + 2) % 3) }
      __builtin_amdgcn_sched_barrier(0);

      const char* Ab = sm + (t % 3) * 16384;
#pragma unroll
      for (int ks = 0; ks < 2; ++ks) {
        f16x8 af[4];
#pragma unroll
        for (int m = 0; m < 4; ++m) {
          const int r = m*16 + lo;
          const int s0 = (ks*8 + hi*2)     ^ (r & 7);
          const int s1 = (ks*8 + hi*2 + 1) ^ (r & 7);
          f32x4 a0 = *reinterpret_cast<const f32x4*>(Ab + r*256 + s0*16);
          f32x4 a1 = *reinterpret_cast<const f32x4*>(Ab + r*256 + s1*16);
          af[m] = cvtp(a0, a1);
        }
#pragma unroll
        for (int m = 0; m < 4; ++m)
#pragma unroll
          for (int n = 0; n < 4; ++n)
            acc[m][n] = __builtin_amdgcn_mfma_f32_16x16x32_f16(
                af[m], ks == 0 ? bf0[n] : bf1[n], acc[m][n], 0, 0, 0);
      }
    }
#undef CH_ISSUE

    __syncthreads();     // ring dead -> reuse first 32KB as T
    // E0 tile -> T (f16, swizzled 512B rows)
#pragma unroll
    for (int m = 0; m < 4; ++m)
#pragma unroll
      for (int n = 0; n < 4; ++n) {
        const int col = wcol + n*16 + lo;
        const float bb = b_er[col];
#pragma unroll
        for (int r = 0; r < 4; ++r) {
          const int rl = m*16 + hi*4 + r;
          const int byte = rl*512 + ((col*2) ^ ((rl & 7) << 4));
          *reinterpret_cast<f16*>(sm + byte) = (f16)(acc[m][n][r] + bb);
        }
      }
  }
  __syncthreads();

  // ---------------- pass S: accS = T @ Wl1^T ----------------
  {
    f32x4 accS[4][4] = {};
    for (int t = 0; t < 4; ++t) {
#pragma unroll
      for (int ks = 0; ks < 2; ++ks) {
        const int kc = t*8 + ks*4 + hi;
        const int b0 = t*128 + ks*64 + hi*16;
        f16x8 af[4], bf[4];
#pragma unroll
        for (int m = 0; m < 4; ++m) {
          const int r = m*16 + lo;
          af[m] = *reinterpret_cast<const f16x8*>(sm + r*512 + (b0 ^ ((r & 7) << 4)));
        }
#pragma unroll
        for (int n = 0; n < 4; ++n)
          bf[n] = *reinterpret_cast<const f16x8*>(Bl1 + ((size_t)kc*256 + (wcol + n*16 + lo)) * 8);
#pragma unroll
        for (int m = 0; m < 4; ++m)
#pragma unroll
          for (int n = 0; n < 4; ++n)
            accS[m][n] = __builtin_amdgcn_mfma_f32_16x16x32_f16(af[m], bf[n], accS[m][n], 0, 0, 0);
      }
    }
#pragma unroll
    for (int m = 0; m < 4; ++m) {
#pragma unroll
      for (int r = 0; r < 4; ++r) {
        float p = 0.f;
#pragma unroll
        for (int n = 0; n < 4; ++n) {
          const int col = wcol + n*16 + lo;
          p += Wl2[col] * fmaxf(accS[m][n][r] + bl1[col], 0.0f);
        }
        p += __shfl_xor(p, 1); p += __shfl_xor(p, 2);
        p += __shfl_xor(p, 4); p += __shfl_xor(p, 8);
        if (lo == 0) red[m*16 + hi*4 + r][wave] = p;
      }
    }
  }

  // ---------------- pass M: accM = T @ Wev^T ----------------
  {
    f32x4 accM[4][4] = {};
    for (int t = 0; t < 4; ++t) {
#pragma unroll
      for (int ks = 0; ks < 2; ++ks) {
        const int kc = t*8 + ks*4 + hi;
        const int b0 = t*128 + ks*64 + hi*16;
        f16x8 af[4], bf[4];
#pragma unroll
        for (int m = 0; m < 4; ++m) {
          const int r = m*16 + lo;
          af[m] = *reinterpret_cast<const f16x8*>(sm + r*512 + (b0 ^ ((r & 7) << 4)));
        }
#pragma unroll
        for (int n = 0; n < 4; ++n)
          bf[n] = *reinterpret_cast<const f16x8*>(Bev + ((size_t)kc*256 + (wcol + n*16 + lo)) * 8);
#pragma unroll
        for (int m = 0; m < 4; ++m)
#pragma unroll
          for (int n = 0; n < 4; ++n)
            accM[m][n] = __builtin_amdgcn_mfma_f32_16x16x32_f16(af[m], bf[n], accM[m][n], 0, 0, 0);
      }
    }
    __syncthreads();   // all T reads done; overwrite with Mpre (linear)
    const int rxb = (blk >> 6) * 64;
#pragma unroll
    for (int m = 0; m < 4; ++m)
#pragma unroll
      for (int n = 0; n < 4; ++n) {
        const int col = wcol + n*16 + lo;
        const float bb = bm[col];
#pragma unroll
        for (int r = 0; r < 4; ++r) {
          const int rl = m*16 + hi*4 + r;
          float v = accM[m][n][r] + XpH[(size_t)(rxb + rl)*256 + col] + bb;
          *reinterpret_cast<f16*>(sm + rl*512 + col*2) = (f16)fmaxf(v, 0.0f);
        }
      }
  }
  __syncthreads();
#pragma unroll
  for (int i = 0; i < 8; ++i) {
    const int lin = i*4096 + tid*16;
    f16x8 v = *reinterpret_cast<const f16x8*>(sm + lin);
    *reinterpret_cast<f16x8*>((char*)Mpreh + arow0*512 + lin) = v;
  }
  if (tid < 64)
    S1[arow0 + tid] = sigmoidf_(bl2[0] + red[tid][0] + red[tid][1] + red[tid][2] + red[tid][3]);
}

// ---------------------------------------------------------------------------
// Score pass 2 (transposed gather, reg-staged) + fused msum.
// XCD-chunked swizzle keeps each batch b's 16MB Mpre region on one XCD L2.
// ---------------------------------------------------------------------------
__global__ __launch_bounds__(256) void attn2_ms(
    const f16* __restrict__ Mpreh, const float* __restrict__ S1,
    const f16* __restrict__ Bl1, const float* __restrict__ bl1,
    const float* __restrict__ Wl2, const float* __restrict__ bl2,
    float* __restrict__ adj, f16* __restrict__ xf)
{
  const int blk = (blockIdx.x & 7) * 128 + (blockIdx.x >> 3);
  const int b = blk >> 6, v = blk & 63;
  const int tid = threadIdx.x;
  const int wave = tid >> 6, l = tid & 63;
  const int lo = l & 15, hi = l >> 4;
  const int wcol = wave * 64;
  __shared__ f16 As[2][64][72];
  __shared__ float red[64][4];
  __shared__ float s1s[64];
  __shared__ float s2s[64];
  f32x4 acc[4][4] = {};
  const int rr0 = tid >> 3, part = tid & 7;
  const size_t pbase = (size_t)b * 4096 + v;
  f16x8 ga, gb;

  if (tid < 64) s1s[tid] = S1[pbase + (size_t)tid * 64];
  __syncthreads();

#define A2_LOAD(T)                                                              \
  { ga = *reinterpret_cast<const f16x8*>(Mpreh + (pbase + (size_t)rr0*64)*256 + (T)*64 + part*8);     \
    gb = *reinterpret_cast<const f16x8*>(Mpreh + (pbase + (size_t)(rr0+32)*64)*256 + (T)*64 + part*8); }
#define A2_WRITE(BUF)                                                           \
  { f16 sa = (f16)s1s[rr0], sb = (f16)s1s[rr0 + 32];                            \
    f16x8 ha = ga, hb = gb;                                                     \
    _Pragma("unroll") for (int j = 0; j < 8; ++j) { ha[j] *= sa; hb[j] *= sb; } \
    *reinterpret_cast<f16x8*>(&As[BUF][rr0][part*8]) = ha;                      \
    *reinterpret_cast<f16x8*>(&As[BUF][rr0 + 32][part*8]) = hb; }

  A2_LOAD(0); A2_WRITE(0);
  for (int t = 0; t < 4; ++t) {
    __syncthreads();
    if (t < 3) A2_LOAD(t + 1);
    const int cur = t & 1;
#pragma unroll
    for (int ks = 0; ks < 2; ++ks) {
      f16x8 af[4], bf[4];
      const int kc = t*8 + ks*4 + hi;
#pragma unroll
      for (int m = 0; m < 4; ++m)
        af[m] = *reinterpret_cast<const f16x8*>(&As[cur][m*16 + lo][ks*32 + hi*8]);
#pragma unroll
      for (int n = 0; n < 4; ++n)
        bf[n] = *reinterpret_cast<const f16x8*>(Bl1 + ((size_t)kc*256 + (wcol + n*16 + lo)) * 8);
#pragma unroll
      for (int m = 0; m < 4; ++m)
#pragma unroll
        for (int n = 0; n < 4; ++n)
          acc[m][n] = __builtin_amdgcn_mfma_f32_16x16x32_f16(af[m], bf[n], acc[m][n], 0, 0, 0);
    }
    if (t < 3) A2_WRITE(cur ^ 1);
  }
#undef A2_LOAD
#undef A2_WRITE
#pragma unroll
  for (int m = 0; m < 4; ++m) {
#pragma unroll
    for (int r = 0; r < 4; ++r) {
      float p = 0.f;
#pragma unroll
      for (int n = 0; n < 4; ++n) {
        const int col = wcol + n*16 + lo;
        p += Wl2[col] * fmaxf(acc[m][n][r] + bl1[col], 0.0f);
      }
      p += __shfl_xor(p, 1); p += __shfl_xor(p, 2);
      p += __shfl_xor(p, 4); p += __shfl_xor(p, 8);
      if (lo == 0) red[m*16 + hi*4 + r][wave] = p;
    }
  }
  __syncthreads();
  if (tid < 64) {
    float s = bl2[0] + red[tid][0] + red[tid][1] + red[tid][2] + red[tid][3];
    adj[(size_t)b*4096 + (size_t)v*64 + tid] = s;
    s2s[tid] = sigmoidf_(s);
  }
  __syncthreads();
  const int c = tid;
  const f16* mp = Mpreh + (size_t)blk * 64 * 256 + c;
  float accx = 0.f;
#pragma unroll 8
  for (int w = 0; w < 64; ++w)
    accx += (float)mp[(size_t)w * 256] * s2s[w];
  xf[(size_t)blk * 256 + c] = (f16)accx;
}

// ---------------------------------------------------------------------------
// Fused Xp + XpH, BM=16, grid 64
// ---------------------------------------------------------------------------
__global__ __launch_bounds__(256) void xp_xph16(
    const float* __restrict__ A, const f16* __restrict__ Bnr,
    const float* __restrict__ b_nr, const f16* __restrict__ Bhw,
    float* __restrict__ Xp, f16* __restrict__ Xpf, float* __restrict__ XpH)
{
  const int tid = threadIdx.x;
  const int wave = tid >> 6, l = tid & 63;
  const int lo = l & 15, hi = l >> 4;
  const int wcol = wave * 64;
  __shared__ f16 As[2][16][72];
  __shared__ f16 XpS[16][264];
  f32x4 acc[4] = {};
  const size_t arow0 = (size_t)blockIdx.x * 16;
  const int srow = tid >> 4, spart = tid & 15;
  const float* abase = A + (arow0 + srow) * FN;
  float4 g;
  const float4 z4 = make_float4(0.f, 0.f, 0.f, 0.f);

#define XQ_LOAD(T)                                                          \
  { int kb = (T)*64 + spart*4;                                              \
    g = (kb + 4 <= FN) ? *(const float4*)(abase + kb) : z4; }
#define XQ_WRITE(BUF)                                                       \
  { *reinterpret_cast<f16x4*>(&As[BUF][srow][spart*4]) = cvtp4(g); }

  XQ_LOAD(0); XQ_WRITE(0);
  for (int t = 0; t < 18; ++t) {
    __syncthreads();
    if (t < 17) XQ_LOAD(t + 1);
    const int cur = t & 1;
#pragma unroll
    for (int ks = 0; ks < 2; ++ks) {
      const int kc = t*8 + ks*4 + hi;
      f16x8 af = *reinterpret_cast<const f16x8*>(&As[cur][lo][ks*32 + hi*8]);
      f16x8 bf[4];
#pragma unroll
      for (int n = 0; n < 4; ++n)
        bf[n] = *reinterpret_cast<const f16x8*>(Bnr + ((size_t)kc*256 + (wcol + n*16 + lo)) * 8);
#pragma unroll
      for (int n = 0; n < 4; ++n)
        acc[n] = __builtin_amdgcn_mfma_f32_16x16x32_f16(af, bf[n], acc[n], 0, 0, 0);
    }
    if (t < 17) XQ_WRITE(cur ^ 1);
  }
#undef XQ_LOAD
#undef XQ_WRITE
#pragma unroll
  for (int n = 0; n < 4; ++n) {
    const int col = wcol + n*16 + lo;
    const float bb = b_nr[col];
#pragma unroll
    for (int r = 0; r < 4; ++r) {
      const size_t row = arow0 + hi*4 + r;
      float v = acc[n][r] + bb;
      Xp[row * 256 + col] = v;
      f16 hv = (f16)v;
      Xpf[row * 256 + col] = hv;
      XpS[hi*4 + r][col] = hv;
    }
  }
  __syncthreads();
  f32x4 acch[4] = {};
  for (int t = 0; t < 4; ++t) {
#pragma unroll
    for (int ks = 0; ks < 2; ++ks) {
      const int kc = t*8 + ks*4 + hi;
      f16x8 af = *reinterpret_cast<const f16x8*>(&XpS[lo][t*64 + ks*32 + hi*8]);
      f16x8 bf[4];
#pragma unroll
      for (int n = 0; n < 4; ++n)
        bf[n] = *reinterpret_cast<const f16x8*>(Bhw + ((size_t)kc*256 + (wcol + n*16 + lo)) * 8);
#pragma unroll
      for (int n = 0; n < 4; ++n)
        acch[n] = __builtin_amdgcn_mfma_f32_16x16x32_f16(af, bf[n], acch[n], 0, 0, 0);
    }
  }
#pragma unroll
  for (int n = 0; n < 4; ++n) {
    const int col = wcol + n*16 + lo;
#pragma unroll
    for (int r = 0; r < 4; ++r)
      XpH[(arow0 + hi*4 + r) * 256 + col] = acch[n][r];
  }
}

// ---------------------------------------------------------------------------
// Merged gi/gh GEMM, BM=16: grid (64, 6)
// ---------------------------------------------------------------------------
__global__ __launch_bounds__(256) void gigh16(
    const f16* __restrict__ xf, const f16* __restrict__ Xpf,
    const f16* __restrict__ Wi8, const f16* __restrict__ Wh8,
    const float* __restrict__ bi, const float* __restrict__ bh,
    float* __restrict__ gi, float* __restrict__ gh)
{
  const int rb = blockIdx.x;
  int cb = blockIdx.y;
  const f16* A; const f16* Bp; const float* bias; float* C;
  if (cb < 3) { A = xf;  Bp = Wi8; bias = bi; C = gi; }
  else        { A = Xpf; Bp = Wh8; bias = bh; C = gh; cb -= 3; }
  const int tid = threadIdx.x;
  const int wave = tid >> 6, l = tid & 63;
  const int lo = l & 15, hi = l >> 4;
  const int wcol = cb * 256 + wave * 64;
  __shared__ f16 As[16][264];
  f32x4 acc[4] = {};
  const size_t arow0 = (size_t)rb * 16;

#pragma unroll
  for (int i = 0; i < 2; ++i) {
    int idx = i * 256 + tid;
    int rr = idx >> 5, part = idx & 31;
    *reinterpret_cast<f16x8*>(&As[rr][part*8]) =
        *reinterpret_cast<const f16x8*>(A + (arow0 + rr)*256 + part*8);
  }
  __syncthreads();

  for (int t = 0; t < 4; ++t) {
#pragma unroll
    for (int ks = 0; ks < 2; ++ks) {
      const int kc = t*8 + ks*4 + hi;
      f16x8 af = *reinterpret_cast<const f16x8*>(&As[lo][t*64 + ks*32 + hi*8]);
      f16x8 bf[4];
#pragma unroll
      for (int n = 0; n < 4; ++n)
        bf[n] = *reinterpret_cast<const f16x8*>(Bp + ((size_t)kc*768 + (wcol + n*16 + lo)) * 8);
#pragma unroll
      for (int n = 0; n < 4; ++n)
        acc[n] = __builtin_amdgcn_mfma_f32_16x16x32_f16(af, bf[n], acc[n], 0, 0, 0);
    }
  }
#pragma unroll
  for (int n = 0; n < 4; ++n) {
    const int col = wcol + n*16 + lo;
    const float bb = bias[col];
#pragma unroll
    for (int r = 0; r < 4; ++r)
      C[(arow0 + hi*4 + r) * 768 + col] = acc[n][r] + bb;
  }
}

// ---------------------------------------------------------------------------
// Labels GEMM with GRU fused into staging, BM=16: grid (64, 3)
// ---------------------------------------------------------------------------
__global__ __launch_bounds__(256) void labels_gru16(
    const float* __restrict__ gi, const float* __restrict__ gh,
    const float* __restrict__ Xp, const f16* __restrict__ Wro8,
    const float* __restrict__ bro, float* __restrict__ labels)
{
  const int rb = blockIdx.x, cb = blockIdx.y;
  const int tid = threadIdx.x;
  const int wave = tid >> 6, l = tid & 63;
  const int lo = l & 15, hi = l >> 4;
  const int wcol = cb * 256 + wave * 64;
  __shared__ f16 As[16][264];
  f32x4 acc[4] = {};
  const size_t arow0 = (size_t)rb * 16;

  {
    const int rr = tid >> 4, c0 = (tid & 15) * 16;
    const float* gir = gi + (arow0 + rr) * 768;
    const float* ghr = gh + (arow0 + rr) * 768;
    const float* xpr = Xp + (arow0 + rr) * 256;
#pragma unroll
    for (int j = 0; j < 16; ++j) {
      const int c = c0 + j;
      float r = sigmoidf_(gir[c] + ghr[c]);
      float z = sigmoidf_(gir[256 + c] + ghr[256 + c]);
      float n = tanhf(gir[512 + c] + r * ghr[512 + c]);
      float h = xpr[c];
      As[rr][c] = (f16)((1.0f - z) * n + z * h);
    }
  }
  __syncthreads();

  for (int t = 0; t < 4; ++t) {
#pragma unroll
    for (int ks = 0; ks < 2; ++ks) {
      const int kc = t*8 + ks*4 + hi;
      f16x8 af = *reinterpret_cast<const f16x8*>(&As[lo][t*64 + ks*32 + hi*8]);
      f16x8 bf[4];
#pragma unroll
      for (int n = 0; n < 4; ++n)
        bf[n] = *reinterpret_cast<const f16x8*>(Wro8 + ((size_t)kc*768 + (wcol + n*16 + lo)) * 8);
#pragma unroll
      for (int n = 0; n < 4; ++n)
        acc[n] = __builtin_amdgcn_mfma_f32_16x16x32_f16(af, bf[n], acc[n], 0, 0, 0);
    }
  }
#pragma unroll
  for (int n = 0; n < 4; ++n) {
    const int col = wcol + n*16 + lo;
    if (col < KC) {
      const float bb = bro[col];
#pragma unroll
      for (int r = 0; r < 4; ++r)
        labels[(arow0 + hi*4 + r) * (size_t)KC + col] = acc[n][r] + bb;
    }
  }
}

} // namespace

extern "C" void kernel_launch(void* const* d_in, const int* in_sizes, int n_in,
                              void* d_out, int out_size, void* d_ws, size_t ws_size,
                              hipStream_t stream)
{
  const float* ef   = (const float*)d_in[0];
  const float* nf   = (const float*)d_in[1];
  const float* W_er = (const float*)d_in[7];
  const float* b_er = (const float*)d_in[8];
  const float* W_nr = (const float*)d_in[9];
  const float* b_nr = (const float*)d_in[10];
  const float* Wl1  = (const float*)d_in[11];
  const float* bl1  = (const float*)d_in[12];
  const float* Wl2  = (const float*)d_in[13];
  const float* bl2  = (const float*)d_in[14];
  const float* Wm   = (const float*)d_in[15];
  const float* bm   = (const float*)d_in[16];
  const float* Wi   = (const float*)d_in[17];
  const float* bi   = (const float*)d_in[18];
  const float* Wh   = (const float*)d_in[19];
  const float* bh   = (const float*)d_in[20];
  const float* Wro  = (const float*)d_in[21];
  const float* bro  = (const float*)d_in[22];

  float* ws = (float*)d_ws;
  float* Xp    = ws + OFF_XP;
  f16*   Xpf   = (f16*)(ws + OFF_XPF);
  float* XpH   = ws + OFF_XPH;
  float* S1    = ws + OFF_S1;
  f16*   xf    = (f16*)(ws + OFF_XF);
  float* gi    = ws + OFF_GI;
  float* gh    = ws + OFF_GH;
  f16*   Wer8  = (f16*)(ws + OFF_WER8);
  f16*   Wnr8  = (f16*)(ws + OFF_WNR8);
  f16*   Wev8  = (f16*)(ws + OFF_WEV8);
  f16*   Whw8  = (f16*)(ws + OFF_WHW8);
  f16*   Wl18  = (f16*)(ws + OFF_WL18);
  f16*   Wi8   = (f16*)(ws + OFF_WI8);
  f16*   Wh8   = (f16*)(ws + OFF_WH8);
  f16*   Wro8  = (f16*)(ws + OFF_WRO8);
  f16*   Mpreh = (f16*)(ws + OFF_MPREH);
  float* adj    = (float*)d_out;
  float* labels = (float*)d_out + PAIRS;

  dim3 blk(256);

  cast_all<<<dim3(680), blk, 0, stream>>>(W_er, W_nr, Wm, Wl1, Wi, Wh, Wro,
                                          Wer8, Wnr8, Wev8, Whw8, Wl18, Wi8, Wh8, Wro8);
  xp_xph16<<<dim3(64), blk, 0, stream>>>(nf, Wnr8, b_nr, Whw8, Xp, Xpf, XpH);
  e0_sm<<<dim3(PAIRS / 64), blk, 0, stream>>>(ef, Wer8, b_er, Wl18, Wev8,
                                              bl1, Wl2, bl2, XpH, bm,
                                              S1, Mpreh);
  attn2_ms<<<dim3(PAIRS / 64), blk, 0, stream>>>(Mpreh, S1, Wl18, bl1, Wl2, bl2,
                                                 adj, xf);
  gigh16<<<dim3(64, 6), blk, 0, stream>>>(xf, Xpf, Wi8, Wh8, bi, bh, gi, gh);
  labels_gru16<<<dim3(64, 3), blk, 0, stream>>>(gi, gh, Xp, Wro8, bro, labels);
}